// Round 1
// 1267.038 us; speedup vs baseline: 1.0909x; 1.0909x over previous
//
#include <hip/hip_runtime.h>

#define BB 2
#define NN 2048
#define DD 1024
#define HH 16
#define HD 64
#define RR (BB * NN)  // 4096 rows
#define CH 32         // scan chunk length (steps per LDS buffer)

typedef __bf16 bf16x8 __attribute__((ext_vector_type(8)));
typedef float f32x4 __attribute__((ext_vector_type(4)));
typedef float f32x2 __attribute__((ext_vector_type(2)));

__device__ __forceinline__ float sigmoidf_(float x) { return 1.f / (1.f + __expf(-x)); }

// Sum of lane and lane^32 partner, entirely in the VALU (no lgkmcnt traffic).
__device__ __forceinline__ float half_swap_add(float x) {
#if __has_builtin(__builtin_amdgcn_permlane32_swap)
    typedef int v2i __attribute__((ext_vector_type(2)));
    v2i r = __builtin_amdgcn_permlane32_swap(__float_as_int(x), __float_as_int(x), false, false);
    return __int_as_float(r[0]) + __int_as_float(r[1]);
#else
    return x + __shfl_xor(x, 32);
#endif
}

// async global -> LDS DMA (gfx950). LDS dst is wave-uniform; lane i's data
// lands at dst + i*size. Global src is a normal per-lane address.
__device__ __forceinline__ void gl2lds16(const float* g, void* l) {
    __builtin_amdgcn_global_load_lds((const __attribute__((address_space(1))) void*)g,
                                     (__attribute__((address_space(3))) void*)l, 16, 0, 0);
}
__device__ __forceinline__ void gl2lds4(const float* g, void* l) {
    __builtin_amdgcn_global_load_lds((const __attribute__((address_space(1))) void*)g,
                                     (__attribute__((address_space(3))) void*)l, 4, 0, 0);
}

// ---------------------------------------------------------------------------
// bf16-MFMA GEMM: C[M,N] = A[M,K] @ B[K,N], fp32 in/out, bf16 compute.
// (unchanged — verified correct)
// ---------------------------------------------------------------------------
__global__ __launch_bounds__(256) void gemm_bf16(const float* __restrict__ A,
                                                 const float* __restrict__ B,
                                                 float* __restrict__ C,
                                                 int M, int N, int K) {
    constexpr int LW = 40;
    __shared__ __align__(16) __bf16 As[128 * LW];
    __shared__ __align__(16) __bf16 Bs[128 * LW];
    const int tid = threadIdx.x;
    const int lane = tid & 63;
    const int wave = tid >> 6;
    const int wm = (wave >> 1) * 64, wn = (wave & 1) * 64;
    const int bm = blockIdx.y * 128, bn = blockIdx.x * 128;
    const int l15 = lane & 15, quad = lane >> 4;

    const int ar = tid >> 1, akc = (tid & 1) * 16;
    const int bcol = tid & 127, bk0 = (tid >> 7) * 16;

    f32x4 acc[4][4];
#pragma unroll
    for (int i = 0; i < 4; i++)
#pragma unroll
        for (int j = 0; j < 4; j++) acc[i][j] = (f32x4){0.f, 0.f, 0.f, 0.f};

    for (int kb = 0; kb < K; kb += 32) {
        float av[16];
        const float* ap = A + (size_t)(bm + ar) * K + kb + akc;
#pragma unroll
        for (int p = 0; p < 4; p++) {
            float4 t = *(const float4*)(ap + 4 * p);
            av[4 * p + 0] = t.x; av[4 * p + 1] = t.y; av[4 * p + 2] = t.z; av[4 * p + 3] = t.w;
        }
        float bv[16];
        const float* bp = B + (size_t)(kb + bk0) * N + bn + bcol;
#pragma unroll
        for (int p = 0; p < 16; p++) bv[p] = bp[(size_t)p * N];

        __syncthreads();
        bf16x8 w0, w1, u0, u1;
#pragma unroll
        for (int p = 0; p < 8; p++) {
            w0[p] = (__bf16)av[p]; w1[p] = (__bf16)av[8 + p];
            u0[p] = (__bf16)bv[p]; u1[p] = (__bf16)bv[8 + p];
        }
        *(bf16x8*)&As[ar * LW + akc] = w0;
        *(bf16x8*)&As[ar * LW + akc + 8] = w1;
        *(bf16x8*)&Bs[bcol * LW + bk0] = u0;
        *(bf16x8*)&Bs[bcol * LW + bk0 + 8] = u1;
        __syncthreads();

        bf16x8 af[4], bfr[4];
#pragma unroll
        for (int i = 0; i < 4; i++)
            af[i] = *(const bf16x8*)&As[(wm + i * 16 + l15) * LW + quad * 8];
#pragma unroll
        for (int j = 0; j < 4; j++)
            bfr[j] = *(const bf16x8*)&Bs[(wn + j * 16 + l15) * LW + quad * 8];
#pragma unroll
        for (int i = 0; i < 4; i++)
#pragma unroll
            for (int j = 0; j < 4; j++)
                acc[i][j] = __builtin_amdgcn_mfma_f32_16x16x32_bf16(af[i], bfr[j], acc[i][j], 0, 0, 0);
    }

#pragma unroll
    for (int i = 0; i < 4; i++) {
#pragma unroll
        for (int r = 0; r < 4; r++) {
            const int row = bm + wm + i * 16 + quad * 4 + r;
            float* cp = C + (size_t)row * N + bn + wn + l15;
#pragma unroll
            for (int j = 0; j < 4; j++) cp[j * 16] = acc[i][j][r];
        }
    }
}

// ---------------------------------------------------------------------------
// Generic fp32 tiled GEMM (used for gate = g1 @ Wg2, K=64). (unchanged)
// ---------------------------------------------------------------------------
__global__ __launch_bounds__(256) void gemm_f32(const float* __restrict__ A,
                                                const float* __restrict__ B,
                                                float* __restrict__ C,
                                                int M, int N, int K) {
    __shared__ float As[16][128];
    __shared__ float Bs[16][128];
    const int tid = threadIdx.x;
    const int bm = blockIdx.y * 128;
    const int bn = blockIdx.x * 128;
    const int tx = tid & 15, ty = tid >> 4;
    const int arow = tid >> 1, ak0 = (tid & 1) * 8;
    const int brow = tid >> 4, bn0 = (tid & 15) * 8;

    float acc[8][8];
#pragma unroll
    for (int i = 0; i < 8; i++)
#pragma unroll
        for (int j = 0; j < 8; j++) acc[i][j] = 0.f;

    for (int kb = 0; kb < K; kb += 16) {
        const float* ap = A + (size_t)(bm + arow) * K + kb + ak0;
        float4 a0 = *(const float4*)(ap);
        float4 a1 = *(const float4*)(ap + 4);
        const int gn = bn + bn0;
        float4 b0 = make_float4(0.f, 0.f, 0.f, 0.f), b1 = b0;
        if (gn < N) {
            const float* bp = B + (size_t)(kb + brow) * N + gn;
            b0 = *(const float4*)(bp);
            b1 = *(const float4*)(bp + 4);
        }
        __syncthreads();
        As[ak0 + 0][arow] = a0.x; As[ak0 + 1][arow] = a0.y;
        As[ak0 + 2][arow] = a0.z; As[ak0 + 3][arow] = a0.w;
        As[ak0 + 4][arow] = a1.x; As[ak0 + 5][arow] = a1.y;
        As[ak0 + 6][arow] = a1.z; As[ak0 + 7][arow] = a1.w;
        *(float4*)&Bs[brow][bn0] = b0;
        *(float4*)&Bs[brow][bn0 + 4] = b1;
        __syncthreads();
#pragma unroll
        for (int kk = 0; kk < 16; kk++) {
            float4 x0 = *(const float4*)&As[kk][ty * 8];
            float4 x1 = *(const float4*)&As[kk][ty * 8 + 4];
            float4 y0 = *(const float4*)&Bs[kk][tx * 8];
            float4 y1 = *(const float4*)&Bs[kk][tx * 8 + 4];
            float xa[8] = {x0.x, x0.y, x0.z, x0.w, x1.x, x1.y, x1.z, x1.w};
            float yb[8] = {y0.x, y0.y, y0.z, y0.w, y1.x, y1.y, y1.z, y1.w};
#pragma unroll
            for (int i = 0; i < 8; i++)
#pragma unroll
                for (int j = 0; j < 8; j++) acc[i][j] += xa[i] * yb[j];
        }
    }
    const int cn = bn + tx * 8;
    if (cn < N) {
#pragma unroll
        for (int i = 0; i < 8; i++) {
            float* cp = C + (size_t)(bm + ty * 8 + i) * N + cn;
            *(float4*)cp = make_float4(acc[i][0], acc[i][1], acc[i][2], acc[i][3]);
            *(float4*)(cp + 4) = make_float4(acc[i][4], acc[i][5], acc[i][6], acc[i][7]);
        }
    }
}

// ---------------------------------------------------------------------------
// Fused skinny projections: [graw|fraw|g1] = x @ [Wgamma|Wf|Wg1]. (unchanged)
// ---------------------------------------------------------------------------
__global__ __launch_bounds__(256) void proj96(const float* __restrict__ x,
                                              const float* __restrict__ Wgm,
                                              const float* __restrict__ Wf,
                                              const float* __restrict__ Wg1,
                                              float* __restrict__ graw,
                                              float* __restrict__ fraw,
                                              float* __restrict__ g1) {
    __shared__ float xs[16][65];
    const int tid = threadIdx.x;
    const int row0 = blockIdx.x * 16;
    const int r = tid >> 4;       // 0..15
    const int cg = tid & 15;      // 0..15

    const float* wp[6];
    int ws[6];
#pragma unroll
    for (int j = 0; j < 6; j++) {
        const int c = cg * 6 + j;  // 0..95
        if (c < 16)      { wp[j] = Wgm + c;        ws[j] = 16; }
        else if (c < 32) { wp[j] = Wf + (c - 16);  ws[j] = 16; }
        else             { wp[j] = Wg1 + (c - 32); ws[j] = 64; }
    }

    float acc[6];
#pragma unroll
    for (int j = 0; j < 6; j++) acc[j] = 0.f;

    const int sr = tid >> 4, sc = (tid & 15) * 4;
    for (int kc = 0; kc < DD; kc += 64) {
        float4 t = *(const float4*)(x + (size_t)(row0 + sr) * DD + kc + sc);
        __syncthreads();
        xs[sr][sc + 0] = t.x; xs[sr][sc + 1] = t.y; xs[sr][sc + 2] = t.z; xs[sr][sc + 3] = t.w;
        __syncthreads();
#pragma unroll 8
        for (int kk = 0; kk < 64; kk++) {
            const float xv = xs[r][kk];
#pragma unroll
            for (int j = 0; j < 6; j++) acc[j] += xv * wp[j][(size_t)(kc + kk) * ws[j]];
        }
    }

#pragma unroll
    for (int j = 0; j < 6; j++) {
        const int c = cg * 6 + j;
        const int gr = row0 + r;
        if (c < 16)      graw[(size_t)gr * 16 + c] = acc[j];
        else if (c < 32) fraw[(size_t)gr * 16 + (c - 16)] = acc[j];
        else             g1[(size_t)gr * 64 + (c - 32)] = acc[j];
    }
}

// ---------------------------------------------------------------------------
// Post-projection elementwise. One wave per (row, head). (unchanged)
// ---------------------------------------------------------------------------
__global__ __launch_bounds__(256) void prep_kernel(float* qb, float* kb, float* vb,
                                                   const float* __restrict__ fraw,
                                                   const float* __restrict__ graw,
                                                   float* lfb, float* csb) {
    const int tid = threadIdx.x;
    const int wav = tid >> 6, lane = tid & 63;
    const int gid = blockIdx.x * 4 + wav;  // (r,h)
    const int r = gid >> 4, h = gid & 15;
    const size_t idx = (size_t)r * DD + (size_t)h * HD + lane;

    float xq = qb[idx], xk = kb[idx], xv = vb[idx];
    float q = xq * sigmoidf_(xq);
    float v = xv * sigmoidf_(xv);
    float kk = xk * sigmoidf_(xk);
    float ss = kk * kk;
#pragma unroll
    for (int m = 1; m <= 32; m <<= 1) ss += __shfl_xor(ss, m);
    float norm = fmaxf(sqrtf(ss), 1e-12f);
    float kn = kk / norm;

    float f = fraw[(size_t)r * HH + h];
    float sig = sigmoidf_(f);                               // lambda
    float gm = -sigmoidf_(graw[(size_t)r * HH + h]);        // gamma

    qb[idx] = q;
    vb[idx] = v;
    kb[idx] = kn;
    if (lane == 0) {
        lfb[(size_t)r * HH + h] = sig;
        csb[(size_t)r * HH + h] = gm * sig * sig;
    }
}

// ---------------------------------------------------------------------------
// Sequential delta-rule scan. Lane = (khalf in 0..1) x (vcol in 0..31).
// Each lane holds 32 k-rows of one v-column of S in 16 f32x2 regs (pk-fp32).
// The ONLY cross-lane op per step is one v_permlane32_swap (VALU — no
// lgkmcnt drain in the recurrence chain, unlike the old ds-based shuffles).
// 64 blocks x 64 threads: 2 v-slices of 32 per (b,h).
// ---------------------------------------------------------------------------
__global__ __launch_bounds__(64) void scan_kernel(const float* __restrict__ qb,
                                                  const float* __restrict__ kb,
                                                  const float* __restrict__ vb,
                                                  const float* __restrict__ lfb,
                                                  const float* __restrict__ csb,
                                                  __bf16* __restrict__ obh) {
    // NO padding: global_load_lds lands lane i at base + i*width (contiguous).
    __shared__ __align__(16) float ks[2][CH][64];
    __shared__ __align__(16) float qs[2][CH][64];
    __shared__ __align__(16) float vs[2][CH][32];
    __shared__ __align__(16) float ms[2][CH][2];  // [t] = {lambda, c}

    const int bx = blockIdx.x;
    const int bh = bx >> 1, wslice = bx & 1;
    const int b = bh >> 4, h = bh & 15;
    const int lane = threadIdx.x;
    const int khalf = lane >> 5;   // which 32 k-rows
    const int vx = lane & 31;      // v column within slice
    const size_t base0 = (size_t)(b * NN) * DD + (size_t)h * HD;
    const size_t lf0 = (size_t)(b * NN) * HH + h;

    // staging lane decompositions (LDS offset == lane*width for each instr)
    const int rk = lane >> 4, ck = (lane & 15) * 4;  // k/q: 4 rows of 64 / instr
    const int rv = lane >> 3, cv = (lane & 7) * 4;   // v: 8 rows of 32 / instr
    const int mt = lane >> 1, msel = lane & 1;       // ms: interleaved {lam,c}

    f32x2 S2[16];
#pragma unroll
    for (int i = 0; i < 16; i++) S2[i] = (f32x2){0.f, 0.f};

    auto stage = [&](int c, int bsel) {
        const int t0 = c * CH;
#pragma unroll
        for (int r0 = 0; r0 < CH; r0 += 4) {
            gl2lds16(kb + base0 + (size_t)(t0 + r0 + rk) * DD + ck, &ks[bsel][r0][0]);
            gl2lds16(qb + base0 + (size_t)(t0 + r0 + rk) * DD + ck, &qs[bsel][r0][0]);
        }
#pragma unroll
        for (int r0 = 0; r0 < CH; r0 += 8) {
            gl2lds16(vb + base0 + (size_t)(t0 + r0 + rv) * DD + wslice * 32 + cv,
                     &vs[bsel][r0][0]);
        }
        // lane -> (t = lane>>1, sel = lane&1): interleave lambda/c pairs
        const float* mg = msel ? (csb + lf0 + (size_t)(t0 + mt) * HH)
                               : (lfb + lf0 + (size_t)(t0 + mt) * HH);
        gl2lds4(mg, &ms[bsel][0][0]);
    };

    stage(0, 0);
    __syncthreads();

    for (int c = 0; c < NN / CH; c++) {
        const int cur = c & 1;
        if (c + 1 < NN / CH) stage(c + 1, cur ^ 1);

        const float* kS = &ks[cur][0][0];
        const float* qS = &qs[cur][0][0];
        const float* vS = &vs[cur][0][0];
        const float* mS = &ms[cur][0][0];
        const int t0 = c * CH;

        f32x4 KF[2][8], QF[2][8];
        float VF[2], LMF[2], CSF[2];
        // preload step 0 into slot 0
        {
            const f32x4* kp = (const f32x4*)(kS + khalf * 32);
            const f32x4* qp = (const f32x4*)(qS + khalf * 32);
#pragma unroll
            for (int j = 0; j < 8; j++) { KF[0][j] = kp[j]; QF[0][j] = qp[j]; }
            VF[0] = vS[vx];
            LMF[0] = mS[0];
            CSF[0] = mS[1];
        }

        for (int tb = 0; tb < CH; tb += 8) {
#pragma unroll
            for (int i = 0; i < 8; i++) {
                const int tt = tb + i;
                const int cs = i & 1, ns = cs ^ 1;
                // prefetch step tt+1 into the other slot (clamp at CH-1)
                const int tn = (tt + 1 < CH) ? tt + 1 : CH - 1;
                {
                    const f32x4* kp = (const f32x4*)(kS + tn * 64 + khalf * 32);
                    const f32x4* qp = (const f32x4*)(qS + tn * 64 + khalf * 32);
#pragma unroll
                    for (int j = 0; j < 8; j++) { KF[ns][j] = kp[j]; QF[ns][j] = qp[j]; }
                    VF[ns] = vS[tn * 32 + vx];
                    LMF[ns] = mS[tn * 2];
                    CSF[ns] = mS[tn * 2 + 1];
                }
                // compute step tt from slot cs — all packed-fp32, one permlane
                const float lam = LMF[cs];
                f32x2 a0 = (f32x2){0.f, 0.f}, a1 = (f32x2){0.f, 0.f};
#pragma unroll
                for (int j = 0; j < 8; j++) {
                    f32x2 kl = __builtin_shufflevector(KF[cs][j], KF[cs][j], 0, 1);
                    f32x2 kh2 = __builtin_shufflevector(KF[cs][j], KF[cs][j], 2, 3);
                    a0 += kl * S2[2 * j];
                    a1 += kh2 * S2[2 * j + 1];
                }
                f32x2 asum = a0 + a1;
                float pu = asum[0] + asum[1];
                pu = half_swap_add(pu);  // sum the two 32-row halves (VALU)
                const float u = CSF[cs] * pu + VF[cs];
                const f32x2 u2 = (f32x2){u, u};
                const f32x2 lam2 = (f32x2){lam, lam};
                f32x2 b0 = (f32x2){0.f, 0.f}, b1 = (f32x2){0.f, 0.f};
#pragma unroll
                for (int j = 0; j < 8; j++) {
                    f32x2 kl = __builtin_shufflevector(KF[cs][j], KF[cs][j], 0, 1);
                    f32x2 kh2 = __builtin_shufflevector(KF[cs][j], KF[cs][j], 2, 3);
                    f32x2 ql = __builtin_shufflevector(QF[cs][j], QF[cs][j], 0, 1);
                    f32x2 qh2 = __builtin_shufflevector(QF[cs][j], QF[cs][j], 2, 3);
                    f32x2 s0 = lam2 * S2[2 * j] + kl * u2;
                    f32x2 s1 = lam2 * S2[2 * j + 1] + kh2 * u2;
                    S2[2 * j] = s0;
                    S2[2 * j + 1] = s1;
                    b0 += ql * s0;
                    b1 += qh2 * s1;
                }
                f32x2 bsum = b0 + b1;
                float po = bsum[0] + bsum[1];
                po = half_swap_add(po);
                if (lane < 32)
                    obh[base0 + (size_t)(t0 + tt) * DD + wslice * 32 + lane] = (__bf16)po;
            }
        }
        // drain this chunk's ds_reads + the in-flight DMA before buffers flip
        asm volatile("s_waitcnt vmcnt(0)" ::: "memory");
        __syncthreads();
    }
}

// ---------------------------------------------------------------------------
// outp = LayerNorm(o * sigmoid(gatep)) * norm_w. o is bf16, result fp32.
// (unchanged)
// ---------------------------------------------------------------------------
__global__ __launch_bounds__(256) void gate_ln_kernel(const __bf16* __restrict__ obh,
                                                      const float* __restrict__ gatep,
                                                      const float* __restrict__ nw,
                                                      float* __restrict__ outp) {
    const int r = blockIdx.x, tid = threadIdx.x;
    const int wav = tid >> 6, lane = tid & 63;
    __shared__ float red[8];
    const size_t rb = (size_t)r * DD;

    float vals[4];
    float s = 0.f;
#pragma unroll
    for (int p = 0; p < 4; p++) {
        const int j = tid + 256 * p;
        float xg = (float)obh[rb + j] * sigmoidf_(gatep[rb + j]);
        vals[p] = xg;
        s += xg;
    }
#pragma unroll
    for (int m = 1; m <= 32; m <<= 1) s += __shfl_xor(s, m);
    if (lane == 0) red[wav] = s;
    __syncthreads();
    const float mu = (red[0] + red[1] + red[2] + red[3]) * (1.f / 1024.f);

    float s2 = 0.f;
#pragma unroll
    for (int p = 0; p < 4; p++) { float d = vals[p] - mu; s2 += d * d; }
#pragma unroll
    for (int m = 1; m <= 32; m <<= 1) s2 += __shfl_xor(s2, m);
    if (lane == 0) red[4 + wav] = s2;
    __syncthreads();
    const float var = (red[4] + red[5] + red[6] + red[7]) * (1.f / 1024.f);
    const float rs = rsqrtf(var + 1e-5f);

#pragma unroll
    for (int p = 0; p < 4; p++) {
        const int j = tid + 256 * p;
        outp[rb + j] = (vals[p] - mu) * rs * nw[j];
    }
}

// ---------------------------------------------------------------------------
extern "C" void kernel_launch(void* const* d_in, const int* in_sizes, int n_in,
                              void* d_out, int out_size, void* d_ws, size_t ws_size,
                              hipStream_t stream) {
    const float* x   = (const float*)d_in[0];
    const float* Wq  = (const float*)d_in[1];
    const float* Wk  = (const float*)d_in[2];
    const float* Wv  = (const float*)d_in[3];
    const float* Wgm = (const float*)d_in[4];  // Wgamma
    const float* Wf  = (const float*)d_in[5];
    const float* Wg1 = (const float*)d_in[6];
    const float* Wg2 = (const float*)d_in[7];
    const float* Wo  = (const float*)d_in[8];
    const float* nw  = (const float*)d_in[9];
    float* out = (float*)d_out;

    float* w = (float*)d_ws;
    float* qb    = w;                   // 4096x1024 f32 (q; later LN output)
    float* kb    = qb + 4194304;
    float* vb    = kb + 4194304;
    float* gatep = vb + 4194304;
    float* fraw  = gatep + 4194304;     // 4096x16
    float* graw  = fraw + 65536;        // 4096x16
    float* g1    = graw + 65536;        // 4096x64
    float* lfb   = g1 + 262144;         // 4096x16 (lambda)
    float* csb   = lfb + 65536;         // 4096x16 (gamma*lambda^2)
    __bf16* obh  = (__bf16*)(csb + 65536);  // 4096x1024 bf16 scan output

    dim3 blk(256);
    gemm_bf16<<<dim3(8, 32), blk, 0, stream>>>(x, Wq, qb, RR, DD, DD);
    gemm_bf16<<<dim3(8, 32), blk, 0, stream>>>(x, Wk, kb, RR, DD, DD);
    gemm_bf16<<<dim3(8, 32), blk, 0, stream>>>(x, Wv, vb, RR, DD, DD);
    proj96<<<RR / 16, blk, 0, stream>>>(x, Wgm, Wf, Wg1, graw, fraw, g1);
    gemm_f32<<<dim3(8, 32), blk, 0, stream>>>(g1, Wg2, gatep, RR, DD, HD);
    prep_kernel<<<RR * HH / 4, blk, 0, stream>>>(qb, kb, vb, fraw, graw, lfb, csb);
    scan_kernel<<<64, 64, 0, stream>>>(qb, kb, vb, lfb, csb, obh);
    gate_ln_kernel<<<RR, blk, 0, stream>>>(obh, gatep, nw, qb);
    gemm_bf16<<<dim3(8, 32), blk, 0, stream>>>(qb, Wo, out, RR, DD, DD);
}

// Round 2
// 764.849 us; speedup vs baseline: 1.8072x; 1.6566x over previous
//
#include <hip/hip_runtime.h>

#define BB 2
#define NN 2048
#define DD 1024
#define HH 16
#define HD 64
#define RR (BB * NN)  // 4096 rows
#define CH 32         // scan chunk length (steps per LDS buffer)

typedef __bf16 bf16x8 __attribute__((ext_vector_type(8)));
typedef float f32x4 __attribute__((ext_vector_type(4)));
typedef float f32x2 __attribute__((ext_vector_type(2)));

__device__ __forceinline__ float sigmoidf_(float x) { return 1.f / (1.f + __expf(-x)); }

// Butterfly add with lane^32 partner, entirely in the VALU (no lgkmcnt).
__device__ __forceinline__ float swap32_add(float x) {
#if __has_builtin(__builtin_amdgcn_permlane32_swap)
    typedef int v2i __attribute__((ext_vector_type(2)));
    v2i r = __builtin_amdgcn_permlane32_swap(__float_as_int(x), __float_as_int(x), false, false);
    return __int_as_float(r[0]) + __int_as_float(r[1]);
#else
    return x + __shfl_xor(x, 32);
#endif
}
// Butterfly add with lane^16 partner, entirely in the VALU.
__device__ __forceinline__ float swap16_add(float x) {
#if __has_builtin(__builtin_amdgcn_permlane16_swap)
    typedef int v2i __attribute__((ext_vector_type(2)));
    v2i r = __builtin_amdgcn_permlane16_swap(__float_as_int(x), __float_as_int(x), false, false);
    return __int_as_float(r[0]) + __int_as_float(r[1]);
#else
    return x + __shfl_xor(x, 16);
#endif
}

// async global -> LDS DMA (gfx950). LDS dst is wave-uniform; lane i's data
// lands at dst + i*size. Global src is a normal per-lane address.
__device__ __forceinline__ void gl2lds16(const float* g, void* l) {
    __builtin_amdgcn_global_load_lds((const __attribute__((address_space(1))) void*)g,
                                     (__attribute__((address_space(3))) void*)l, 16, 0, 0);
}
__device__ __forceinline__ void gl2lds4(const float* g, void* l) {
    __builtin_amdgcn_global_load_lds((const __attribute__((address_space(1))) void*)g,
                                     (__attribute__((address_space(3))) void*)l, 4, 0, 0);
}

// ---------------------------------------------------------------------------
// bf16-MFMA GEMM: C[M,N] = A[M,K] @ B[K,N], fp32 in/out, bf16 compute.
// (unchanged — verified correct)
// ---------------------------------------------------------------------------
__global__ __launch_bounds__(256) void gemm_bf16(const float* __restrict__ A,
                                                 const float* __restrict__ B,
                                                 float* __restrict__ C,
                                                 int M, int N, int K) {
    constexpr int LW = 40;
    __shared__ __align__(16) __bf16 As[128 * LW];
    __shared__ __align__(16) __bf16 Bs[128 * LW];
    const int tid = threadIdx.x;
    const int lane = tid & 63;
    const int wave = tid >> 6;
    const int wm = (wave >> 1) * 64, wn = (wave & 1) * 64;
    const int bm = blockIdx.y * 128, bn = blockIdx.x * 128;
    const int l15 = lane & 15, quad = lane >> 4;

    const int ar = tid >> 1, akc = (tid & 1) * 16;
    const int bcol = tid & 127, bk0 = (tid >> 7) * 16;

    f32x4 acc[4][4];
#pragma unroll
    for (int i = 0; i < 4; i++)
#pragma unroll
        for (int j = 0; j < 4; j++) acc[i][j] = (f32x4){0.f, 0.f, 0.f, 0.f};

    for (int kb = 0; kb < K; kb += 32) {
        float av[16];
        const float* ap = A + (size_t)(bm + ar) * K + kb + akc;
#pragma unroll
        for (int p = 0; p < 4; p++) {
            float4 t = *(const float4*)(ap + 4 * p);
            av[4 * p + 0] = t.x; av[4 * p + 1] = t.y; av[4 * p + 2] = t.z; av[4 * p + 3] = t.w;
        }
        float bv[16];
        const float* bp = B + (size_t)(kb + bk0) * N + bn + bcol;
#pragma unroll
        for (int p = 0; p < 16; p++) bv[p] = bp[(size_t)p * N];

        __syncthreads();
        bf16x8 w0, w1, u0, u1;
#pragma unroll
        for (int p = 0; p < 8; p++) {
            w0[p] = (__bf16)av[p]; w1[p] = (__bf16)av[8 + p];
            u0[p] = (__bf16)bv[p]; u1[p] = (__bf16)bv[8 + p];
        }
        *(bf16x8*)&As[ar * LW + akc] = w0;
        *(bf16x8*)&As[ar * LW + akc + 8] = w1;
        *(bf16x8*)&Bs[bcol * LW + bk0] = u0;
        *(bf16x8*)&Bs[bcol * LW + bk0 + 8] = u1;
        __syncthreads();

        bf16x8 af[4], bfr[4];
#pragma unroll
        for (int i = 0; i < 4; i++)
            af[i] = *(const bf16x8*)&As[(wm + i * 16 + l15) * LW + quad * 8];
#pragma unroll
        for (int j = 0; j < 4; j++)
            bfr[j] = *(const bf16x8*)&Bs[(wn + j * 16 + l15) * LW + quad * 8];
#pragma unroll
        for (int i = 0; i < 4; i++)
#pragma unroll
            for (int j = 0; j < 4; j++)
                acc[i][j] = __builtin_amdgcn_mfma_f32_16x16x32_bf16(af[i], bfr[j], acc[i][j], 0, 0, 0);
    }

#pragma unroll
    for (int i = 0; i < 4; i++) {
#pragma unroll
        for (int r = 0; r < 4; r++) {
            const int row = bm + wm + i * 16 + quad * 4 + r;
            float* cp = C + (size_t)row * N + bn + wn + l15;
#pragma unroll
            for (int j = 0; j < 4; j++) cp[j * 16] = acc[i][j][r];
        }
    }
}

// ---------------------------------------------------------------------------
// Generic fp32 tiled GEMM (used for gate = g1 @ Wg2, K=64). (unchanged)
// ---------------------------------------------------------------------------
__global__ __launch_bounds__(256) void gemm_f32(const float* __restrict__ A,
                                                const float* __restrict__ B,
                                                float* __restrict__ C,
                                                int M, int N, int K) {
    __shared__ float As[16][128];
    __shared__ float Bs[16][128];
    const int tid = threadIdx.x;
    const int bm = blockIdx.y * 128;
    const int bn = blockIdx.x * 128;
    const int tx = tid & 15, ty = tid >> 4;
    const int arow = tid >> 1, ak0 = (tid & 1) * 8;
    const int brow = tid >> 4, bn0 = (tid & 15) * 8;

    float acc[8][8];
#pragma unroll
    for (int i = 0; i < 8; i++)
#pragma unroll
        for (int j = 0; j < 8; j++) acc[i][j] = 0.f;

    for (int kb = 0; kb < K; kb += 16) {
        const float* ap = A + (size_t)(bm + arow) * K + kb + ak0;
        float4 a0 = *(const float4*)(ap);
        float4 a1 = *(const float4*)(ap + 4);
        const int gn = bn + bn0;
        float4 b0 = make_float4(0.f, 0.f, 0.f, 0.f), b1 = b0;
        if (gn < N) {
            const float* bp = B + (size_t)(kb + brow) * N + gn;
            b0 = *(const float4*)(bp);
            b1 = *(const float4*)(bp + 4);
        }
        __syncthreads();
        As[ak0 + 0][arow] = a0.x; As[ak0 + 1][arow] = a0.y;
        As[ak0 + 2][arow] = a0.z; As[ak0 + 3][arow] = a0.w;
        As[ak0 + 4][arow] = a1.x; As[ak0 + 5][arow] = a1.y;
        As[ak0 + 6][arow] = a1.z; As[ak0 + 7][arow] = a1.w;
        *(float4*)&Bs[brow][bn0] = b0;
        *(float4*)&Bs[brow][bn0 + 4] = b1;
        __syncthreads();
#pragma unroll
        for (int kk = 0; kk < 16; kk++) {
            float4 x0 = *(const float4*)&As[kk][ty * 8];
            float4 x1 = *(const float4*)&As[kk][ty * 8 + 4];
            float4 y0 = *(const float4*)&Bs[kk][tx * 8];
            float4 y1 = *(const float4*)&Bs[kk][tx * 8 + 4];
            float xa[8] = {x0.x, x0.y, x0.z, x0.w, x1.x, x1.y, x1.z, x1.w};
            float yb[8] = {y0.x, y0.y, y0.z, y0.w, y1.x, y1.y, y1.z, y1.w};
#pragma unroll
            for (int i = 0; i < 8; i++)
#pragma unroll
                for (int j = 0; j < 8; j++) acc[i][j] += xa[i] * yb[j];
        }
    }
    const int cn = bn + tx * 8;
    if (cn < N) {
#pragma unroll
        for (int i = 0; i < 8; i++) {
            float* cp = C + (size_t)(bm + ty * 8 + i) * N + cn;
            *(float4*)cp = make_float4(acc[i][0], acc[i][1], acc[i][2], acc[i][3]);
            *(float4*)(cp + 4) = make_float4(acc[i][4], acc[i][5], acc[i][6], acc[i][7]);
        }
    }
}

// ---------------------------------------------------------------------------
// Fused skinny projections: [graw|fraw|g1] = x @ [Wgamma|Wf|Wg1]  (96 cols).
// REWRITE: per 64-k chunk, stage W[64][96] (padded row 100) and transposed
// x[64][32] in LDS; inner loop is conflict-free ds_read_b64 + packed FMA.
// Block: 32 rows x 96 cols; thread (ty=tid>>4 -> 2 rows, cg=tid&15 -> 6 cols).
// ---------------------------------------------------------------------------
__global__ __launch_bounds__(256) void proj96(const float* __restrict__ x,
                                              const float* __restrict__ Wgm,
                                              const float* __restrict__ Wf,
                                              const float* __restrict__ Wg1,
                                              float* __restrict__ graw,
                                              float* __restrict__ fraw,
                                              float* __restrict__ g1) {
    __shared__ float xs[64][32];    // [k][row]
    __shared__ float Ws[64][100];   // [k][col], row padded 96->100 (bank spread)
    const int tid = threadIdx.x;
    const int row0 = blockIdx.x * 32;
    const int ty = tid >> 4;   // 0..15 -> rows ty*2, ty*2+1
    const int cg = tid & 15;   // cols cg*6 .. cg*6+5

    // staging decompositions
    const int trow = tid >> 3, tcol8 = (tid & 7) * 8;  // x: row, 8-col group
    const int wk = tid >> 2;                           // 0..63 (W row)
    const int wc4 = (tid & 3) * 4;                     // Wgm/Wf 4-col group
    const int wq = tid & 3;                            // Wg1 16-col quarter

    f32x2 acc[6];
#pragma unroll
    for (int j = 0; j < 6; j++) acc[j] = (f32x2){0.f, 0.f};

    for (int kc = 0; kc < DD; kc += 64) {
        const float* xp = x + (size_t)(row0 + trow) * DD + kc + tcol8;
        float4 xa = *(const float4*)(xp);
        float4 xb = *(const float4*)(xp + 4);
        float4 wg = *(const float4*)(Wgm + (size_t)(kc + wk) * 16 + wc4);
        float4 wf = *(const float4*)(Wf + (size_t)(kc + wk) * 16 + wc4);
        float4 w1[4];
#pragma unroll
        for (int p = 0; p < 4; p++)
            w1[p] = *(const float4*)(Wg1 + (size_t)(kc + wk) * 64 + wq * 16 + p * 4);

        __syncthreads();
        xs[tcol8 + 0][trow] = xa.x; xs[tcol8 + 1][trow] = xa.y;
        xs[tcol8 + 2][trow] = xa.z; xs[tcol8 + 3][trow] = xa.w;
        xs[tcol8 + 4][trow] = xb.x; xs[tcol8 + 5][trow] = xb.y;
        xs[tcol8 + 6][trow] = xb.z; xs[tcol8 + 7][trow] = xb.w;
        *(float4*)&Ws[wk][wc4] = wg;
        *(float4*)&Ws[wk][16 + wc4] = wf;
#pragma unroll
        for (int p = 0; p < 4; p++) *(float4*)&Ws[wk][32 + wq * 16 + p * 4] = w1[p];
        __syncthreads();

#pragma unroll 4
        for (int kk = 0; kk < 64; kk++) {
            const f32x2 xv = *(const f32x2*)&xs[kk][ty * 2];
            const f32x2 w01 = *(const f32x2*)&Ws[kk][cg * 6];
            const f32x2 w23 = *(const f32x2*)&Ws[kk][cg * 6 + 2];
            const f32x2 w45 = *(const f32x2*)&Ws[kk][cg * 6 + 4];
            acc[0] += xv * (f32x2){w01[0], w01[0]};
            acc[1] += xv * (f32x2){w01[1], w01[1]};
            acc[2] += xv * (f32x2){w23[0], w23[0]};
            acc[3] += xv * (f32x2){w23[1], w23[1]};
            acc[4] += xv * (f32x2){w45[0], w45[0]};
            acc[5] += xv * (f32x2){w45[1], w45[1]};
        }
    }

#pragma unroll
    for (int j = 0; j < 6; j++) {
        const int c = cg * 6 + j;
#pragma unroll
        for (int r = 0; r < 2; r++) {
            const int gr = row0 + ty * 2 + r;
            const float val = acc[j][r];
            if (c < 16)      graw[(size_t)gr * 16 + c] = val;
            else if (c < 32) fraw[(size_t)gr * 16 + (c - 16)] = val;
            else             g1[(size_t)gr * 64 + (c - 32)] = val;
        }
    }
}

// ---------------------------------------------------------------------------
// Post-projection elementwise. One wave per (row, head). (unchanged)
// ---------------------------------------------------------------------------
__global__ __launch_bounds__(256) void prep_kernel(float* qb, float* kb, float* vb,
                                                   const float* __restrict__ fraw,
                                                   const float* __restrict__ graw,
                                                   float* lfb, float* csb) {
    const int tid = threadIdx.x;
    const int wav = tid >> 6, lane = tid & 63;
    const int gid = blockIdx.x * 4 + wav;  // (r,h)
    const int r = gid >> 4, h = gid & 15;
    const size_t idx = (size_t)r * DD + (size_t)h * HD + lane;

    float xq = qb[idx], xk = kb[idx], xv = vb[idx];
    float q = xq * sigmoidf_(xq);
    float v = xv * sigmoidf_(xv);
    float kk = xk * sigmoidf_(xk);
    float ss = kk * kk;
#pragma unroll
    for (int m = 1; m <= 32; m <<= 1) ss += __shfl_xor(ss, m);
    float norm = fmaxf(sqrtf(ss), 1e-12f);
    float kn = kk / norm;

    float f = fraw[(size_t)r * HH + h];
    float sig = sigmoidf_(f);                               // lambda
    float gm = -sigmoidf_(graw[(size_t)r * HH + h]);        // gamma

    qb[idx] = q;
    vb[idx] = v;
    kb[idx] = kn;
    if (lane == 0) {
        lfb[(size_t)r * HH + h] = sig;
        csb[(size_t)r * HH + h] = gm * sig * sig;
    }
}

// ---------------------------------------------------------------------------
// Sequential delta-rule scan. Lane = (kq in 0..3) x (vloc in 0..15):
// small register fragment (16 k + 16 q floats, 8 ds_read_b128/step) so the
// one-step-ahead register pipeline stays live (no compiler load-sinking),
// and BOTH reduction hops (lane^16, lane^32) are VALU permlane swaps —
// zero DS ops in the recurrence chain. 128 blocks x 64 threads.
// ---------------------------------------------------------------------------
__global__ __launch_bounds__(64) void scan_kernel(const float* __restrict__ qb,
                                                  const float* __restrict__ kb,
                                                  const float* __restrict__ vb,
                                                  const float* __restrict__ lfb,
                                                  const float* __restrict__ csb,
                                                  __bf16* __restrict__ obh) {
    // NO padding: global_load_lds lands lane i at base + i*width (contiguous).
    __shared__ __align__(16) float ks[2][CH][64];
    __shared__ __align__(16) float qs[2][CH][64];
    __shared__ __align__(16) float vs[2][CH][16];
    __shared__ __align__(16) float ms[2][CH][2];  // [t] = {lambda, c}

    const int bx = blockIdx.x;
    const int bh = bx >> 2, wslice = bx & 3;
    const int b = bh >> 4, h = bh & 15;
    const int lane = threadIdx.x;
    const int kq = lane >> 4;      // which 16 k-rows
    const int vloc = lane & 15;    // v column within slice
    const size_t base0 = (size_t)(b * NN) * DD + (size_t)h * HD;
    const size_t lf0 = (size_t)(b * NN) * HH + h;

    // staging lane decompositions (LDS offset == lane*width for each instr)
    const int rk = lane >> 4, ck = (lane & 15) * 4;  // k/q: 4 rows of 64 / instr
    const int rv = lane >> 2, cv = (lane & 3) * 4;   // v: 16 rows of 16 / instr
    const int mt = lane >> 1, msel = lane & 1;       // ms: interleaved {lam,c}

    f32x2 S2[8];
#pragma unroll
    for (int i = 0; i < 8; i++) S2[i] = (f32x2){0.f, 0.f};

    auto stage = [&](int c, int bsel) {
        const int t0 = c * CH;
#pragma unroll
        for (int r0 = 0; r0 < CH; r0 += 4) {
            gl2lds16(kb + base0 + (size_t)(t0 + r0 + rk) * DD + ck, &ks[bsel][r0][0]);
            gl2lds16(qb + base0 + (size_t)(t0 + r0 + rk) * DD + ck, &qs[bsel][r0][0]);
        }
#pragma unroll
        for (int r0 = 0; r0 < CH; r0 += 16) {
            gl2lds16(vb + base0 + (size_t)(t0 + r0 + rv) * DD + wslice * 16 + cv,
                     &vs[bsel][r0][0]);
        }
        // lane -> (t = lane>>1, sel = lane&1): interleave lambda/c pairs
        const float* mg = msel ? (csb + lf0 + (size_t)(t0 + mt) * HH)
                               : (lfb + lf0 + (size_t)(t0 + mt) * HH);
        gl2lds4(mg, &ms[bsel][0][0]);
    };

    stage(0, 0);
    asm volatile("s_waitcnt vmcnt(0)" ::: "memory");
    __syncthreads();

    for (int c = 0; c < NN / CH; c++) {
        const int cur = c & 1;
        if (c + 1 < NN / CH) stage(c + 1, cur ^ 1);

        const float* kS = &ks[cur][0][0];
        const float* qS = &qs[cur][0][0];
        const float* vS = &vs[cur][0][0];
        const float* mS = &ms[cur][0][0];
        const int t0 = c * CH;

        f32x4 KF[2][4], QF[2][4];
        float VF[2], LMF[2], CSF[2];
        // preload step 0 into slot 0
        {
            const f32x4* kp = (const f32x4*)(kS + kq * 16);
            const f32x4* qp = (const f32x4*)(qS + kq * 16);
#pragma unroll
            for (int j = 0; j < 4; j++) { KF[0][j] = kp[j]; QF[0][j] = qp[j]; }
            VF[0] = vS[vloc];
            f32x2 mm = *(const f32x2*)&mS[0];
            LMF[0] = mm[0]; CSF[0] = mm[1];
        }

        for (int tb = 0; tb < CH; tb += 8) {
#pragma unroll
            for (int i = 0; i < 8; i++) {
                const int tt = tb + i;
                const int cs = i & 1, ns = cs ^ 1;
                // prefetch step tt+1 into the other slot (clamp at CH-1)
                const int tn = (tt + 1 < CH) ? tt + 1 : CH - 1;
                {
                    const f32x4* kp = (const f32x4*)(kS + tn * 64 + kq * 16);
                    const f32x4* qp = (const f32x4*)(qS + tn * 64 + kq * 16);
#pragma unroll
                    for (int j = 0; j < 4; j++) { KF[ns][j] = kp[j]; QF[ns][j] = qp[j]; }
                    VF[ns] = vS[tn * 16 + vloc];
                    f32x2 mm = *(const f32x2*)&mS[tn * 2];
                    LMF[ns] = mm[0]; CSF[ns] = mm[1];
                }
                // compute step tt from slot cs — packed fp32, permlane reduces
                const float lam = LMF[cs];
                f32x2 a0 = (f32x2){0.f, 0.f}, a1 = (f32x2){0.f, 0.f};
#pragma unroll
                for (int j = 0; j < 4; j++) {
                    f32x2 kl = __builtin_shufflevector(KF[cs][j], KF[cs][j], 0, 1);
                    f32x2 kh2 = __builtin_shufflevector(KF[cs][j], KF[cs][j], 2, 3);
                    a0 += kl * S2[2 * j];
                    a1 += kh2 * S2[2 * j + 1];
                }
                f32x2 asum = a0 + a1;
                float pu = asum[0] + asum[1];
                pu = swap16_add(pu);
                pu = swap32_add(pu);
                const float u = CSF[cs] * pu + VF[cs];
                const f32x2 u2 = (f32x2){u, u};
                const f32x2 lam2 = (f32x2){lam, lam};
                f32x2 b0 = (f32x2){0.f, 0.f}, b1 = (f32x2){0.f, 0.f};
#pragma unroll
                for (int j = 0; j < 4; j++) {
                    f32x2 kl = __builtin_shufflevector(KF[cs][j], KF[cs][j], 0, 1);
                    f32x2 kh2 = __builtin_shufflevector(KF[cs][j], KF[cs][j], 2, 3);
                    f32x2 ql = __builtin_shufflevector(QF[cs][j], QF[cs][j], 0, 1);
                    f32x2 qh2 = __builtin_shufflevector(QF[cs][j], QF[cs][j], 2, 3);
                    f32x2 s0 = lam2 * S2[2 * j] + kl * u2;
                    f32x2 s1 = lam2 * S2[2 * j + 1] + kh2 * u2;
                    S2[2 * j] = s0;
                    S2[2 * j + 1] = s1;
                    b0 += ql * s0;
                    b1 += qh2 * s1;
                }
                f32x2 bsum = b0 + b1;
                float po = bsum[0] + bsum[1];
                po = swap16_add(po);
                po = swap32_add(po);
                if (lane < 16)
                    obh[base0 + (size_t)(t0 + tt) * DD + wslice * 16 + lane] = (__bf16)po;
            }
        }
        // drain in-flight DMA before buffers flip
        asm volatile("s_waitcnt vmcnt(0)" ::: "memory");
        __syncthreads();
    }
}

// ---------------------------------------------------------------------------
// outp = LayerNorm(o * sigmoid(gatep)) * norm_w. o is bf16, result fp32.
// (unchanged)
// ---------------------------------------------------------------------------
__global__ __launch_bounds__(256) void gate_ln_kernel(const __bf16* __restrict__ obh,
                                                      const float* __restrict__ gatep,
                                                      const float* __restrict__ nw,
                                                      float* __restrict__ outp) {
    const int r = blockIdx.x, tid = threadIdx.x;
    const int wav = tid >> 6, lane = tid & 63;
    __shared__ float red[8];
    const size_t rb = (size_t)r * DD;

    float vals[4];
    float s = 0.f;
#pragma unroll
    for (int p = 0; p < 4; p++) {
        const int j = tid + 256 * p;
        float xg = (float)obh[rb + j] * sigmoidf_(gatep[rb + j]);
        vals[p] = xg;
        s += xg;
    }
#pragma unroll
    for (int m = 1; m <= 32; m <<= 1) s += __shfl_xor(s, m);
    if (lane == 0) red[wav] = s;
    __syncthreads();
    const float mu = (red[0] + red[1] + red[2] + red[3]) * (1.f / 1024.f);

    float s2 = 0.f;
#pragma unroll
    for (int p = 0; p < 4; p++) { float d = vals[p] - mu; s2 += d * d; }
#pragma unroll
    for (int m = 1; m <= 32; m <<= 1) s2 += __shfl_xor(s2, m);
    if (lane == 0) red[4 + wav] = s2;
    __syncthreads();
    const float var = (red[4] + red[5] + red[6] + red[7]) * (1.f / 1024.f);
    const float rs = rsqrtf(var + 1e-5f);

#pragma unroll
    for (int p = 0; p < 4; p++) {
        const int j = tid + 256 * p;
        outp[rb + j] = (vals[p] - mu) * rs * nw[j];
    }
}

// ---------------------------------------------------------------------------
extern "C" void kernel_launch(void* const* d_in, const int* in_sizes, int n_in,
                              void* d_out, int out_size, void* d_ws, size_t ws_size,
                              hipStream_t stream) {
    const float* x   = (const float*)d_in[0];
    const float* Wq  = (const float*)d_in[1];
    const float* Wk  = (const float*)d_in[2];
    const float* Wv  = (const float*)d_in[3];
    const float* Wgm = (const float*)d_in[4];  // Wgamma
    const float* Wf  = (const float*)d_in[5];
    const float* Wg1 = (const float*)d_in[6];
    const float* Wg2 = (const float*)d_in[7];
    const float* Wo  = (const float*)d_in[8];
    const float* nw  = (const float*)d_in[9];
    float* out = (float*)d_out;

    float* w = (float*)d_ws;
    float* qb    = w;                   // 4096x1024 f32 (q; later LN output)
    float* kb    = qb + 4194304;
    float* vb    = kb + 4194304;
    float* gatep = vb + 4194304;
    float* fraw  = gatep + 4194304;     // 4096x16
    float* graw  = fraw + 65536;        // 4096x16
    float* g1    = graw + 65536;        // 4096x64
    float* lfb   = g1 + 262144;         // 4096x16 (lambda)
    float* csb   = lfb + 65536;         // 4096x16 (gamma*lambda^2)
    __bf16* obh  = (__bf16*)(csb + 65536);  // 4096x1024 bf16 scan output

    dim3 blk(256);
    gemm_bf16<<<dim3(8, 32), blk, 0, stream>>>(x, Wq, qb, RR, DD, DD);
    gemm_bf16<<<dim3(8, 32), blk, 0, stream>>>(x, Wk, kb, RR, DD, DD);
    gemm_bf16<<<dim3(8, 32), blk, 0, stream>>>(x, Wv, vb, RR, DD, DD);
    proj96<<<128, blk, 0, stream>>>(x, Wgm, Wf, Wg1, graw, fraw, g1);
    gemm_f32<<<dim3(8, 32), blk, 0, stream>>>(g1, Wg2, gatep, RR, DD, HD);
    prep_kernel<<<RR * HH / 4, blk, 0, stream>>>(qb, kb, vb, fraw, graw, lfb, csb);
    scan_kernel<<<128, 64, 0, stream>>>(qb, kb, vb, lfb, csb, obh);
    gate_ln_kernel<<<RR, blk, 0, stream>>>(obh, gatep, nw, qb);
    gemm_bf16<<<dim3(8, 32), blk, 0, stream>>>(qb, Wo, out, RR, DD, DD);
}

// Round 3
// 619.284 us; speedup vs baseline: 2.2320x; 1.2351x over previous
//
#include <hip/hip_runtime.h>

#define BB 2
#define NN 2048
#define DD 1024
#define HH 16
#define HD 64
#define RR (BB * NN)  // 4096 rows
#define CH 32         // scan chunk length (steps per LDS buffer)

typedef __bf16 bf16x8 __attribute__((ext_vector_type(8)));
typedef float f32x4 __attribute__((ext_vector_type(4)));
typedef float f32x2 __attribute__((ext_vector_type(2)));

__device__ __forceinline__ float sigmoidf_(float x) { return 1.f / (1.f + __expf(-x)); }

// Butterfly add with lane^32 partner, entirely in the VALU (no lgkmcnt).
__device__ __forceinline__ float swap32_add(float x) {
#if __has_builtin(__builtin_amdgcn_permlane32_swap)
    typedef int v2i __attribute__((ext_vector_type(2)));
    v2i r = __builtin_amdgcn_permlane32_swap(__float_as_int(x), __float_as_int(x), false, false);
    return __int_as_float(r[0]) + __int_as_float(r[1]);
#else
    return x + __shfl_xor(x, 32);
#endif
}
// Butterfly add with lane^16 partner, entirely in the VALU.
__device__ __forceinline__ float swap16_add(float x) {
#if __has_builtin(__builtin_amdgcn_permlane16_swap)
    typedef int v2i __attribute__((ext_vector_type(2)));
    v2i r = __builtin_amdgcn_permlane16_swap(__float_as_int(x), __float_as_int(x), false, false);
    return __int_as_float(r[0]) + __int_as_float(r[1]);
#else
    return x + __shfl_xor(x, 16);
#endif
}
// Butterfly add with lane^8 partner via DPP row_ror:8 (VALU, no lgkmcnt).
// Within each 16-lane row, (i+8)%16 == i^8.
__device__ __forceinline__ float ror8_add(float x) {
    int m = __builtin_amdgcn_update_dpp(0, __float_as_int(x), 0x128, 0xF, 0xF, true);
    return x + __int_as_float(m);
}

// async global -> LDS DMA (gfx950). LDS dst is wave-uniform; lane i's data
// lands at dst + i*size. Global src is a normal per-lane address.
__device__ __forceinline__ void gl2lds16(const float* g, void* l) {
    __builtin_amdgcn_global_load_lds((const __attribute__((address_space(1))) void*)g,
                                     (__attribute__((address_space(3))) void*)l, 16, 0, 0);
}
__device__ __forceinline__ void gl2lds4(const float* g, void* l) {
    __builtin_amdgcn_global_load_lds((const __attribute__((address_space(1))) void*)g,
                                     (__attribute__((address_space(3))) void*)l, 4, 0, 0);
}

// ---------------------------------------------------------------------------
// bf16-MFMA GEMM: C[M,N] = A[M,K] @ B[K,N], fp32 in/out, bf16 compute.
// Block-selected B/C pointers: grid.x = 8*nmat; mat = blockIdx.x>>3 picks
// (B,C) pair. For a single matrix pass the same pointer 3x and grid.x=8.
// Body identical to the round-verified gemm.
// ---------------------------------------------------------------------------
__global__ __launch_bounds__(256) void gemm_bf16(const float* __restrict__ A,
                                                 const float* B0, const float* B1,
                                                 const float* B2,
                                                 float* C0, float* C1, float* C2,
                                                 int M, int N, int K) {
    constexpr int LW = 40;
    __shared__ __align__(16) __bf16 As[128 * LW];
    __shared__ __align__(16) __bf16 Bs[128 * LW];
    const int mat = blockIdx.x >> 3;
    const float* B = (mat == 0) ? B0 : ((mat == 1) ? B1 : B2);
    float* C = (mat == 0) ? C0 : ((mat == 1) ? C1 : C2);
    const int tid = threadIdx.x;
    const int lane = tid & 63;
    const int wave = tid >> 6;
    const int wm = (wave >> 1) * 64, wn = (wave & 1) * 64;
    const int bm = blockIdx.y * 128, bn = (blockIdx.x & 7) * 128;
    const int l15 = lane & 15, quad = lane >> 4;

    const int ar = tid >> 1, akc = (tid & 1) * 16;
    const int bcol = tid & 127, bk0 = (tid >> 7) * 16;

    f32x4 acc[4][4];
#pragma unroll
    for (int i = 0; i < 4; i++)
#pragma unroll
        for (int j = 0; j < 4; j++) acc[i][j] = (f32x4){0.f, 0.f, 0.f, 0.f};

    for (int kb = 0; kb < K; kb += 32) {
        float av[16];
        const float* ap = A + (size_t)(bm + ar) * K + kb + akc;
#pragma unroll
        for (int p = 0; p < 4; p++) {
            float4 t = *(const float4*)(ap + 4 * p);
            av[4 * p + 0] = t.x; av[4 * p + 1] = t.y; av[4 * p + 2] = t.z; av[4 * p + 3] = t.w;
        }
        float bv[16];
        const float* bp = B + (size_t)(kb + bk0) * N + bn + bcol;
#pragma unroll
        for (int p = 0; p < 16; p++) bv[p] = bp[(size_t)p * N];

        __syncthreads();
        bf16x8 w0, w1, u0, u1;
#pragma unroll
        for (int p = 0; p < 8; p++) {
            w0[p] = (__bf16)av[p]; w1[p] = (__bf16)av[8 + p];
            u0[p] = (__bf16)bv[p]; u1[p] = (__bf16)bv[8 + p];
        }
        *(bf16x8*)&As[ar * LW + akc] = w0;
        *(bf16x8*)&As[ar * LW + akc + 8] = w1;
        *(bf16x8*)&Bs[bcol * LW + bk0] = u0;
        *(bf16x8*)&Bs[bcol * LW + bk0 + 8] = u1;
        __syncthreads();

        bf16x8 af[4], bfr[4];
#pragma unroll
        for (int i = 0; i < 4; i++)
            af[i] = *(const bf16x8*)&As[(wm + i * 16 + l15) * LW + quad * 8];
#pragma unroll
        for (int j = 0; j < 4; j++)
            bfr[j] = *(const bf16x8*)&Bs[(wn + j * 16 + l15) * LW + quad * 8];
#pragma unroll
        for (int i = 0; i < 4; i++)
#pragma unroll
            for (int j = 0; j < 4; j++)
                acc[i][j] = __builtin_amdgcn_mfma_f32_16x16x32_bf16(af[i], bfr[j], acc[i][j], 0, 0, 0);
    }

#pragma unroll
    for (int i = 0; i < 4; i++) {
#pragma unroll
        for (int r = 0; r < 4; r++) {
            const int row = bm + wm + i * 16 + quad * 4 + r;
            float* cp = C + (size_t)row * N + bn + wn + l15;
#pragma unroll
            for (int j = 0; j < 4; j++) cp[j * 16] = acc[i][j][r];
        }
    }
}

// ---------------------------------------------------------------------------
// Generic fp32 tiled GEMM (used for gate = g1 @ Wg2, K=64). (unchanged)
// ---------------------------------------------------------------------------
__global__ __launch_bounds__(256) void gemm_f32(const float* __restrict__ A,
                                                const float* __restrict__ B,
                                                float* __restrict__ C,
                                                int M, int N, int K) {
    __shared__ float As[16][128];
    __shared__ float Bs[16][128];
    const int tid = threadIdx.x;
    const int bm = blockIdx.y * 128;
    const int bn = blockIdx.x * 128;
    const int tx = tid & 15, ty = tid >> 4;
    const int arow = tid >> 1, ak0 = (tid & 1) * 8;
    const int brow = tid >> 4, bn0 = (tid & 15) * 8;

    float acc[8][8];
#pragma unroll
    for (int i = 0; i < 8; i++)
#pragma unroll
        for (int j = 0; j < 8; j++) acc[i][j] = 0.f;

    for (int kb = 0; kb < K; kb += 16) {
        const float* ap = A + (size_t)(bm + arow) * K + kb + ak0;
        float4 a0 = *(const float4*)(ap);
        float4 a1 = *(const float4*)(ap + 4);
        const int gn = bn + bn0;
        float4 b0 = make_float4(0.f, 0.f, 0.f, 0.f), b1 = b0;
        if (gn < N) {
            const float* bp = B + (size_t)(kb + brow) * N + gn;
            b0 = *(const float4*)(bp);
            b1 = *(const float4*)(bp + 4);
        }
        __syncthreads();
        As[ak0 + 0][arow] = a0.x; As[ak0 + 1][arow] = a0.y;
        As[ak0 + 2][arow] = a0.z; As[ak0 + 3][arow] = a0.w;
        As[ak0 + 4][arow] = a1.x; As[ak0 + 5][arow] = a1.y;
        As[ak0 + 6][arow] = a1.z; As[ak0 + 7][arow] = a1.w;
        *(float4*)&Bs[brow][bn0] = b0;
        *(float4*)&Bs[brow][bn0 + 4] = b1;
        __syncthreads();
#pragma unroll
        for (int kk = 0; kk < 16; kk++) {
            float4 x0 = *(const float4*)&As[kk][ty * 8];
            float4 x1 = *(const float4*)&As[kk][ty * 8 + 4];
            float4 y0 = *(const float4*)&Bs[kk][tx * 8];
            float4 y1 = *(const float4*)&Bs[kk][tx * 8 + 4];
            float xa[8] = {x0.x, x0.y, x0.z, x0.w, x1.x, x1.y, x1.z, x1.w};
            float yb[8] = {y0.x, y0.y, y0.z, y0.w, y1.x, y1.y, y1.z, y1.w};
#pragma unroll
            for (int i = 0; i < 8; i++)
#pragma unroll
                for (int j = 0; j < 8; j++) acc[i][j] += xa[i] * yb[j];
        }
    }
    const int cn = bn + tx * 8;
    if (cn < N) {
#pragma unroll
        for (int i = 0; i < 8; i++) {
            float* cp = C + (size_t)(bm + ty * 8 + i) * N + cn;
            *(float4*)cp = make_float4(acc[i][0], acc[i][1], acc[i][2], acc[i][3]);
            *(float4*)(cp + 4) = make_float4(acc[i][4], acc[i][5], acc[i][6], acc[i][7]);
        }
    }
}

// ---------------------------------------------------------------------------
// Fused skinny projections: [graw|fraw|g1] = x @ [Wgamma|Wf|Wg1]. (unchanged,
// round-2 verified)
// ---------------------------------------------------------------------------
__global__ __launch_bounds__(256) void proj96(const float* __restrict__ x,
                                              const float* __restrict__ Wgm,
                                              const float* __restrict__ Wf,
                                              const float* __restrict__ Wg1,
                                              float* __restrict__ graw,
                                              float* __restrict__ fraw,
                                              float* __restrict__ g1) {
    __shared__ float xs[64][32];    // [k][row]
    __shared__ float Ws[64][100];   // [k][col], row padded 96->100 (bank spread)
    const int tid = threadIdx.x;
    const int row0 = blockIdx.x * 32;
    const int ty = tid >> 4;   // 0..15 -> rows ty*2, ty*2+1
    const int cg = tid & 15;   // cols cg*6 .. cg*6+5

    // staging decompositions
    const int trow = tid >> 3, tcol8 = (tid & 7) * 8;  // x: row, 8-col group
    const int wk = tid >> 2;                           // 0..63 (W row)
    const int wc4 = (tid & 3) * 4;                     // Wgm/Wf 4-col group
    const int wq = tid & 3;                            // Wg1 16-col quarter

    f32x2 acc[6];
#pragma unroll
    for (int j = 0; j < 6; j++) acc[j] = (f32x2){0.f, 0.f};

    for (int kc = 0; kc < DD; kc += 64) {
        const float* xp = x + (size_t)(row0 + trow) * DD + kc + tcol8;
        float4 xa = *(const float4*)(xp);
        float4 xb = *(const float4*)(xp + 4);
        float4 wg = *(const float4*)(Wgm + (size_t)(kc + wk) * 16 + wc4);
        float4 wf = *(const float4*)(Wf + (size_t)(kc + wk) * 16 + wc4);
        float4 w1[4];
#pragma unroll
        for (int p = 0; p < 4; p++)
            w1[p] = *(const float4*)(Wg1 + (size_t)(kc + wk) * 64 + wq * 16 + p * 4);

        __syncthreads();
        xs[tcol8 + 0][trow] = xa.x; xs[tcol8 + 1][trow] = xa.y;
        xs[tcol8 + 2][trow] = xa.z; xs[tcol8 + 3][trow] = xa.w;
        xs[tcol8 + 4][trow] = xb.x; xs[tcol8 + 5][trow] = xb.y;
        xs[tcol8 + 6][trow] = xb.z; xs[tcol8 + 7][trow] = xb.w;
        *(float4*)&Ws[wk][wc4] = wg;
        *(float4*)&Ws[wk][16 + wc4] = wf;
#pragma unroll
        for (int p = 0; p < 4; p++) *(float4*)&Ws[wk][32 + wq * 16 + p * 4] = w1[p];
        __syncthreads();

#pragma unroll 4
        for (int kk = 0; kk < 64; kk++) {
            const f32x2 xv = *(const f32x2*)&xs[kk][ty * 2];
            const f32x2 w01 = *(const f32x2*)&Ws[kk][cg * 6];
            const f32x2 w23 = *(const f32x2*)&Ws[kk][cg * 6 + 2];
            const f32x2 w45 = *(const f32x2*)&Ws[kk][cg * 6 + 4];
            acc[0] += xv * (f32x2){w01[0], w01[0]};
            acc[1] += xv * (f32x2){w01[1], w01[1]};
            acc[2] += xv * (f32x2){w23[0], w23[0]};
            acc[3] += xv * (f32x2){w23[1], w23[1]};
            acc[4] += xv * (f32x2){w45[0], w45[0]};
            acc[5] += xv * (f32x2){w45[1], w45[1]};
        }
    }

#pragma unroll
    for (int j = 0; j < 6; j++) {
        const int c = cg * 6 + j;
#pragma unroll
        for (int r = 0; r < 2; r++) {
            const int gr = row0 + ty * 2 + r;
            const float val = acc[j][r];
            if (c < 16)      graw[(size_t)gr * 16 + c] = val;
            else if (c < 32) fraw[(size_t)gr * 16 + (c - 16)] = val;
            else             g1[(size_t)gr * 64 + (c - 32)] = val;
        }
    }
}

// ---------------------------------------------------------------------------
// Post-projection elementwise. One wave per (row, head). (unchanged)
// ---------------------------------------------------------------------------
__global__ __launch_bounds__(256) void prep_kernel(float* qb, float* kb, float* vb,
                                                   const float* __restrict__ fraw,
                                                   const float* __restrict__ graw,
                                                   float* lfb, float* csb) {
    const int tid = threadIdx.x;
    const int wav = tid >> 6, lane = tid & 63;
    const int gid = blockIdx.x * 4 + wav;  // (r,h)
    const int r = gid >> 4, h = gid & 15;
    const size_t idx = (size_t)r * DD + (size_t)h * HD + lane;

    float xq = qb[idx], xk = kb[idx], xv = vb[idx];
    float q = xq * sigmoidf_(xq);
    float v = xv * sigmoidf_(xv);
    float kk = xk * sigmoidf_(xk);
    float ss = kk * kk;
#pragma unroll
    for (int m = 1; m <= 32; m <<= 1) ss += __shfl_xor(ss, m);
    float norm = fmaxf(sqrtf(ss), 1e-12f);
    float kn = kk / norm;

    float f = fraw[(size_t)r * HH + h];
    float sig = sigmoidf_(f);                               // lambda
    float gm = -sigmoidf_(graw[(size_t)r * HH + h]);        // gamma

    qb[idx] = q;
    vb[idx] = v;
    kb[idx] = kn;
    if (lane == 0) {
        lfb[(size_t)r * HH + h] = sig;
        csb[(size_t)r * HH + h] = gm * sig * sig;
    }
}

// ---------------------------------------------------------------------------
// Sequential delta-rule scan. Lane = (kq in 0..7) x (vloc in 0..7):
// 8-way k-split, 8-col v-slices -> 256 blocks (one per CU). Per step only
// 2+2 ds_read_b128 (k,q) + 1 b32 (v) + 1 b64 (lam,c). All THREE reduction
// hops (lane^8 via DPP row_ror:8, lane^16 / lane^32 via permlane swaps) are
// pure VALU — zero DS ops in the recurrence chain.
// ---------------------------------------------------------------------------
__global__ __launch_bounds__(64) void scan_kernel(const float* __restrict__ qb,
                                                  const float* __restrict__ kb,
                                                  const float* __restrict__ vb,
                                                  const float* __restrict__ lfb,
                                                  const float* __restrict__ csb,
                                                  __bf16* __restrict__ obh) {
    // NO padding: global_load_lds lands lane i at base + i*width (contiguous).
    __shared__ __align__(16) float ks[2][CH][64];
    __shared__ __align__(16) float qs[2][CH][64];
    __shared__ __align__(16) float vs[2][CH][8];
    __shared__ __align__(16) float ms[2][CH][2];  // [t] = {lambda, c}

    const int bx = blockIdx.x;
    const int bh = bx >> 3, wslice = bx & 7;   // 32 (b,h) x 8 v-slices
    const int b = bh >> 4, h = bh & 15;
    const int lane = threadIdx.x;
    const int kq = lane >> 3;      // which 8 k-rows (0..7)
    const int vloc = lane & 7;     // v column within 8-col slice
    const size_t base0 = (size_t)(b * NN) * DD + (size_t)h * HD;
    const size_t lf0 = (size_t)(b * NN) * HH + h;

    // staging lane decompositions (LDS offset == lane*width for each instr)
    const int rk = lane >> 4, ck = (lane & 15) * 4;  // k/q: 4 rows of 64 / instr
    const int rv = lane >> 1, cv = (lane & 1) * 4;   // v: 32 rows of 8 / instr
    const int mt = lane >> 1, msel = lane & 1;       // ms: interleaved {lam,c}

    f32x2 S2[4];
#pragma unroll
    for (int i = 0; i < 4; i++) S2[i] = (f32x2){0.f, 0.f};

    auto stage = [&](int c, int bsel) {
        const int t0 = c * CH;
#pragma unroll
        for (int r0 = 0; r0 < CH; r0 += 4) {
            gl2lds16(kb + base0 + (size_t)(t0 + r0 + rk) * DD + ck, &ks[bsel][r0][0]);
            gl2lds16(qb + base0 + (size_t)(t0 + r0 + rk) * DD + ck, &qs[bsel][r0][0]);
        }
        // all CH rows of the 8-col v slice in ONE instruction (64 lanes x 16B)
        gl2lds16(vb + base0 + (size_t)(t0 + rv) * DD + wslice * 8 + cv,
                 &vs[bsel][0][0]);
        // lane -> (t = lane>>1, sel = lane&1): interleave lambda/c pairs
        const float* mg = msel ? (csb + lf0 + (size_t)(t0 + mt) * HH)
                               : (lfb + lf0 + (size_t)(t0 + mt) * HH);
        gl2lds4(mg, &ms[bsel][0][0]);
    };

    stage(0, 0);
    asm volatile("s_waitcnt vmcnt(0)" ::: "memory");
    __syncthreads();

    for (int c = 0; c < NN / CH; c++) {
        const int cur = c & 1;
        if (c + 1 < NN / CH) stage(c + 1, cur ^ 1);

        const float* kS = &ks[cur][0][0];
        const float* qS = &qs[cur][0][0];
        const float* vS = &vs[cur][0][0];
        const float* mS = &ms[cur][0][0];
        const int t0 = c * CH;

        f32x4 KF[2][2], QF[2][2];
        float VF[2], LMF[2], CSF[2];
        // preload step 0 into slot 0
        {
            const f32x4* kp = (const f32x4*)(kS + kq * 8);
            const f32x4* qp = (const f32x4*)(qS + kq * 8);
#pragma unroll
            for (int j = 0; j < 2; j++) { KF[0][j] = kp[j]; QF[0][j] = qp[j]; }
            VF[0] = vS[vloc];
            f32x2 mm = *(const f32x2*)&mS[0];
            LMF[0] = mm[0]; CSF[0] = mm[1];
        }

        for (int tb = 0; tb < CH; tb += 8) {
#pragma unroll
            for (int i = 0; i < 8; i++) {
                const int tt = tb + i;
                const int cs = i & 1, ns = cs ^ 1;
                // prefetch step tt+1 into the other slot (clamp at CH-1)
                const int tn = (tt + 1 < CH) ? tt + 1 : CH - 1;
                {
                    const f32x4* kp = (const f32x4*)(kS + tn * 64 + kq * 8);
                    const f32x4* qp = (const f32x4*)(qS + tn * 64 + kq * 8);
#pragma unroll
                    for (int j = 0; j < 2; j++) { KF[ns][j] = kp[j]; QF[ns][j] = qp[j]; }
                    VF[ns] = vS[tn * 8 + vloc];
                    f32x2 mm = *(const f32x2*)&mS[tn * 2];
                    LMF[ns] = mm[0]; CSF[ns] = mm[1];
                }
                // compute step tt from slot cs — packed fp32, VALU-only reduces
                const float lam = LMF[cs];
                f32x2 a0 = (f32x2){0.f, 0.f}, a1 = (f32x2){0.f, 0.f};
#pragma unroll
                for (int j = 0; j < 2; j++) {
                    f32x2 kl = __builtin_shufflevector(KF[cs][j], KF[cs][j], 0, 1);
                    f32x2 kh2 = __builtin_shufflevector(KF[cs][j], KF[cs][j], 2, 3);
                    a0 += kl * S2[2 * j];
                    a1 += kh2 * S2[2 * j + 1];
                }
                f32x2 asum = a0 + a1;
                float pu = asum[0] + asum[1];
                pu = ror8_add(pu);
                pu = swap16_add(pu);
                pu = swap32_add(pu);
                const float u = CSF[cs] * pu + VF[cs];
                const f32x2 u2 = (f32x2){u, u};
                const f32x2 lam2 = (f32x2){lam, lam};
                f32x2 b0 = (f32x2){0.f, 0.f}, b1 = (f32x2){0.f, 0.f};
#pragma unroll
                for (int j = 0; j < 2; j++) {
                    f32x2 kl = __builtin_shufflevector(KF[cs][j], KF[cs][j], 0, 1);
                    f32x2 kh2 = __builtin_shufflevector(KF[cs][j], KF[cs][j], 2, 3);
                    f32x2 ql = __builtin_shufflevector(QF[cs][j], QF[cs][j], 0, 1);
                    f32x2 qh2 = __builtin_shufflevector(QF[cs][j], QF[cs][j], 2, 3);
                    f32x2 s0 = lam2 * S2[2 * j] + kl * u2;
                    f32x2 s1 = lam2 * S2[2 * j + 1] + kh2 * u2;
                    S2[2 * j] = s0;
                    S2[2 * j + 1] = s1;
                    b0 += ql * s0;
                    b1 += qh2 * s1;
                }
                f32x2 bsum = b0 + b1;
                float po = bsum[0] + bsum[1];
                po = ror8_add(po);
                po = swap16_add(po);
                po = swap32_add(po);
                if (lane < 8)
                    obh[base0 + (size_t)(t0 + tt) * DD + wslice * 8 + lane] = (__bf16)po;
            }
        }
        // drain in-flight DMA before buffers flip
        asm volatile("s_waitcnt vmcnt(0)" ::: "memory");
        __syncthreads();
    }
}

// ---------------------------------------------------------------------------
// outp = LayerNorm(o * sigmoid(gatep)) * norm_w. o is bf16, result fp32.
// (unchanged)
// ---------------------------------------------------------------------------
__global__ __launch_bounds__(256) void gate_ln_kernel(const __bf16* __restrict__ obh,
                                                      const float* __restrict__ gatep,
                                                      const float* __restrict__ nw,
                                                      float* __restrict__ outp) {
    const int r = blockIdx.x, tid = threadIdx.x;
    const int wav = tid >> 6, lane = tid & 63;
    __shared__ float red[8];
    const size_t rb = (size_t)r * DD;

    float vals[4];
    float s = 0.f;
#pragma unroll
    for (int p = 0; p < 4; p++) {
        const int j = tid + 256 * p;
        float xg = (float)obh[rb + j] * sigmoidf_(gatep[rb + j]);
        vals[p] = xg;
        s += xg;
    }
#pragma unroll
    for (int m = 1; m <= 32; m <<= 1) s += __shfl_xor(s, m);
    if (lane == 0) red[wav] = s;
    __syncthreads();
    const float mu = (red[0] + red[1] + red[2] + red[3]) * (1.f / 1024.f);

    float s2 = 0.f;
#pragma unroll
    for (int p = 0; p < 4; p++) { float d = vals[p] - mu; s2 += d * d; }
#pragma unroll
    for (int m = 1; m <= 32; m <<= 1) s2 += __shfl_xor(s2, m);
    if (lane == 0) red[4 + wav] = s2;
    __syncthreads();
    const float var = (red[4] + red[5] + red[6] + red[7]) * (1.f / 1024.f);
    const float rs = rsqrtf(var + 1e-5f);

#pragma unroll
    for (int p = 0; p < 4; p++) {
        const int j = tid + 256 * p;
        outp[rb + j] = (vals[p] - mu) * rs * nw[j];
    }
}

// ---------------------------------------------------------------------------
extern "C" void kernel_launch(void* const* d_in, const int* in_sizes, int n_in,
                              void* d_out, int out_size, void* d_ws, size_t ws_size,
                              hipStream_t stream) {
    const float* x   = (const float*)d_in[0];
    const float* Wq  = (const float*)d_in[1];
    const float* Wk  = (const float*)d_in[2];
    const float* Wv  = (const float*)d_in[3];
    const float* Wgm = (const float*)d_in[4];  // Wgamma
    const float* Wf  = (const float*)d_in[5];
    const float* Wg1 = (const float*)d_in[6];
    const float* Wg2 = (const float*)d_in[7];
    const float* Wo  = (const float*)d_in[8];
    const float* nw  = (const float*)d_in[9];
    float* out = (float*)d_out;

    float* w = (float*)d_ws;
    float* qb    = w;                   // 4096x1024 f32 (q; later LN output)
    float* kb    = qb + 4194304;
    float* vb    = kb + 4194304;
    float* gatep = vb + 4194304;
    float* fraw  = gatep + 4194304;     // 4096x16
    float* graw  = fraw + 65536;        // 4096x16
    float* g1    = graw + 65536;        // 4096x64
    float* lfb   = g1 + 262144;         // 4096x16 (lambda)
    float* csb   = lfb + 65536;         // 4096x16 (gamma*lambda^2)
    __bf16* obh  = (__bf16*)(csb + 65536);  // 4096x1024 bf16 scan output

    dim3 blk(256);
    // fused q,k,v projections: 24 x-blocks = 3 matrices x 8 col-tiles
    gemm_bf16<<<dim3(24, 32), blk, 0, stream>>>(x, Wq, Wk, Wv, qb, kb, vb, RR, DD, DD);
    proj96<<<128, blk, 0, stream>>>(x, Wgm, Wf, Wg1, graw, fraw, g1);
    gemm_f32<<<dim3(8, 32), blk, 0, stream>>>(g1, Wg2, gatep, RR, DD, HD);
    prep_kernel<<<RR * HH / 4, blk, 0, stream>>>(qb, kb, vb, fraw, graw, lfb, csb);
    scan_kernel<<<256, 64, 0, stream>>>(qb, kb, vb, lfb, csb, obh);
    gate_ln_kernel<<<RR, blk, 0, stream>>>(obh, gatep, nw, qb);
    gemm_bf16<<<dim3(8, 32), blk, 0, stream>>>(qb, Wo, Wo, Wo, out, out, out, RR, DD, DD);
}

// Round 4
// 362.559 us; speedup vs baseline: 3.8125x; 1.7081x over previous
//
#include <hip/hip_runtime.h>

#define BB 2
#define NN 2048
#define DD 1024
#define HH 16
#define HD 64
#define RR (BB * NN)  // 4096 rows
#define CT 32         // chunk length (steps)
#define NC (NN / CT)  // 64 chunks per (b,h)

typedef __bf16 bf16x8 __attribute__((ext_vector_type(8)));
typedef __bf16 bf16x4 __attribute__((ext_vector_type(4)));
typedef float f32x4 __attribute__((ext_vector_type(4)));
typedef float f32x2 __attribute__((ext_vector_type(2)));

__device__ __forceinline__ float sigmoidf_(float x) { return 1.f / (1.f + __expf(-x)); }

#define MFMA16(a, b, c) __builtin_amdgcn_mfma_f32_16x16x32_bf16((a), (b), (c), 0, 0, 0)

// ---------------------------------------------------------------------------
// bf16-MFMA GEMM: C[M,N] = A[M,K] @ B[K,N], fp32 in/out, bf16 compute.
// Block-selected B/C pointers: grid.x = 8*nmat. (unchanged — verified)
// ---------------------------------------------------------------------------
__global__ __launch_bounds__(256) void gemm_bf16(const float* __restrict__ A,
                                                 const float* B0, const float* B1,
                                                 const float* B2,
                                                 float* C0, float* C1, float* C2,
                                                 int M, int N, int K) {
    constexpr int LW = 40;
    __shared__ __align__(16) __bf16 As[128 * LW];
    __shared__ __align__(16) __bf16 Bs[128 * LW];
    const int mat = blockIdx.x >> 3;
    const float* B = (mat == 0) ? B0 : ((mat == 1) ? B1 : B2);
    float* C = (mat == 0) ? C0 : ((mat == 1) ? C1 : C2);
    const int tid = threadIdx.x;
    const int lane = tid & 63;
    const int wave = tid >> 6;
    const int wm = (wave >> 1) * 64, wn = (wave & 1) * 64;
    const int bm = blockIdx.y * 128, bn = (blockIdx.x & 7) * 128;
    const int l15 = lane & 15, quad = lane >> 4;

    const int ar = tid >> 1, akc = (tid & 1) * 16;
    const int bcol = tid & 127, bk0 = (tid >> 7) * 16;

    f32x4 acc[4][4];
#pragma unroll
    for (int i = 0; i < 4; i++)
#pragma unroll
        for (int j = 0; j < 4; j++) acc[i][j] = (f32x4){0.f, 0.f, 0.f, 0.f};

    for (int kb = 0; kb < K; kb += 32) {
        float av[16];
        const float* ap = A + (size_t)(bm + ar) * K + kb + akc;
#pragma unroll
        for (int p = 0; p < 4; p++) {
            float4 t = *(const float4*)(ap + 4 * p);
            av[4 * p + 0] = t.x; av[4 * p + 1] = t.y; av[4 * p + 2] = t.z; av[4 * p + 3] = t.w;
        }
        float bv[16];
        const float* bp = B + (size_t)(kb + bk0) * N + bn + bcol;
#pragma unroll
        for (int p = 0; p < 16; p++) bv[p] = bp[(size_t)p * N];

        __syncthreads();
        bf16x8 w0, w1, u0, u1;
#pragma unroll
        for (int p = 0; p < 8; p++) {
            w0[p] = (__bf16)av[p]; w1[p] = (__bf16)av[8 + p];
            u0[p] = (__bf16)bv[p]; u1[p] = (__bf16)bv[8 + p];
        }
        *(bf16x8*)&As[ar * LW + akc] = w0;
        *(bf16x8*)&As[ar * LW + akc + 8] = w1;
        *(bf16x8*)&Bs[bcol * LW + bk0] = u0;
        *(bf16x8*)&Bs[bcol * LW + bk0 + 8] = u1;
        __syncthreads();

        bf16x8 af[4], bfr[4];
#pragma unroll
        for (int i = 0; i < 4; i++)
            af[i] = *(const bf16x8*)&As[(wm + i * 16 + l15) * LW + quad * 8];
#pragma unroll
        for (int j = 0; j < 4; j++)
            bfr[j] = *(const bf16x8*)&Bs[(wn + j * 16 + l15) * LW + quad * 8];
#pragma unroll
        for (int i = 0; i < 4; i++)
#pragma unroll
            for (int j = 0; j < 4; j++)
                acc[i][j] = MFMA16(af[i], bfr[j], acc[i][j]);
    }

#pragma unroll
    for (int i = 0; i < 4; i++) {
#pragma unroll
        for (int r = 0; r < 4; r++) {
            const int row = bm + wm + i * 16 + quad * 4 + r;
            float* cp = C + (size_t)row * N + bn + wn + l15;
#pragma unroll
            for (int j = 0; j < 4; j++) cp[j * 16] = acc[i][j][r];
        }
    }
}

// ---------------------------------------------------------------------------
// Generic fp32 tiled GEMM (used for gate = g1 @ Wg2, K=64). (unchanged)
// ---------------------------------------------------------------------------
__global__ __launch_bounds__(256) void gemm_f32(const float* __restrict__ A,
                                                const float* __restrict__ B,
                                                float* __restrict__ C,
                                                int M, int N, int K) {
    __shared__ float As[16][128];
    __shared__ float Bs[16][128];
    const int tid = threadIdx.x;
    const int bm = blockIdx.y * 128;
    const int bn = blockIdx.x * 128;
    const int tx = tid & 15, ty = tid >> 4;
    const int arow = tid >> 1, ak0 = (tid & 1) * 8;
    const int brow = tid >> 4, bn0 = (tid & 15) * 8;

    float acc[8][8];
#pragma unroll
    for (int i = 0; i < 8; i++)
#pragma unroll
        for (int j = 0; j < 8; j++) acc[i][j] = 0.f;

    for (int kb = 0; kb < K; kb += 16) {
        const float* ap = A + (size_t)(bm + arow) * K + kb + ak0;
        float4 a0 = *(const float4*)(ap);
        float4 a1 = *(const float4*)(ap + 4);
        const int gn = bn + bn0;
        float4 b0 = make_float4(0.f, 0.f, 0.f, 0.f), b1 = b0;
        if (gn < N) {
            const float* bp = B + (size_t)(kb + brow) * N + gn;
            b0 = *(const float4*)(bp);
            b1 = *(const float4*)(bp + 4);
        }
        __syncthreads();
        As[ak0 + 0][arow] = a0.x; As[ak0 + 1][arow] = a0.y;
        As[ak0 + 2][arow] = a0.z; As[ak0 + 3][arow] = a0.w;
        As[ak0 + 4][arow] = a1.x; As[ak0 + 5][arow] = a1.y;
        As[ak0 + 6][arow] = a1.z; As[ak0 + 7][arow] = a1.w;
        *(float4*)&Bs[brow][bn0] = b0;
        *(float4*)&Bs[brow][bn0 + 4] = b1;
        __syncthreads();
#pragma unroll
        for (int kk = 0; kk < 16; kk++) {
            float4 x0 = *(const float4*)&As[kk][ty * 8];
            float4 x1 = *(const float4*)&As[kk][ty * 8 + 4];
            float4 y0 = *(const float4*)&Bs[kk][tx * 8];
            float4 y1 = *(const float4*)&Bs[kk][tx * 8 + 4];
            float xa[8] = {x0.x, x0.y, x0.z, x0.w, x1.x, x1.y, x1.z, x1.w};
            float yb[8] = {y0.x, y0.y, y0.z, y0.w, y1.x, y1.y, y1.z, y1.w};
#pragma unroll
            for (int i = 0; i < 8; i++)
#pragma unroll
                for (int j = 0; j < 8; j++) acc[i][j] += xa[i] * yb[j];
        }
    }
    const int cn = bn + tx * 8;
    if (cn < N) {
#pragma unroll
        for (int i = 0; i < 8; i++) {
            float* cp = C + (size_t)(bm + ty * 8 + i) * N + cn;
            *(float4*)cp = make_float4(acc[i][0], acc[i][1], acc[i][2], acc[i][3]);
            *(float4*)(cp + 4) = make_float4(acc[i][4], acc[i][5], acc[i][6], acc[i][7]);
        }
    }
}

// ---------------------------------------------------------------------------
// Fused skinny projections: [graw|fraw|g1] = x @ [Wgamma|Wf|Wg1]. (unchanged)
// ---------------------------------------------------------------------------
__global__ __launch_bounds__(256) void proj96(const float* __restrict__ x,
                                              const float* __restrict__ Wgm,
                                              const float* __restrict__ Wf,
                                              const float* __restrict__ Wg1,
                                              float* __restrict__ graw,
                                              float* __restrict__ fraw,
                                              float* __restrict__ g1) {
    __shared__ float xs[64][32];
    __shared__ float Ws[64][100];
    const int tid = threadIdx.x;
    const int row0 = blockIdx.x * 32;
    const int ty = tid >> 4;
    const int cg = tid & 15;

    const int trow = tid >> 3, tcol8 = (tid & 7) * 8;
    const int wk = tid >> 2;
    const int wc4 = (tid & 3) * 4;
    const int wq = tid & 3;

    f32x2 acc[6];
#pragma unroll
    for (int j = 0; j < 6; j++) acc[j] = (f32x2){0.f, 0.f};

    for (int kc = 0; kc < DD; kc += 64) {
        const float* xp = x + (size_t)(row0 + trow) * DD + kc + tcol8;
        float4 xa = *(const float4*)(xp);
        float4 xb = *(const float4*)(xp + 4);
        float4 wg = *(const float4*)(Wgm + (size_t)(kc + wk) * 16 + wc4);
        float4 wf = *(const float4*)(Wf + (size_t)(kc + wk) * 16 + wc4);
        float4 w1[4];
#pragma unroll
        for (int p = 0; p < 4; p++)
            w1[p] = *(const float4*)(Wg1 + (size_t)(kc + wk) * 64 + wq * 16 + p * 4);

        __syncthreads();
        xs[tcol8 + 0][trow] = xa.x; xs[tcol8 + 1][trow] = xa.y;
        xs[tcol8 + 2][trow] = xa.z; xs[tcol8 + 3][trow] = xa.w;
        xs[tcol8 + 4][trow] = xb.x; xs[tcol8 + 5][trow] = xb.y;
        xs[tcol8 + 6][trow] = xb.z; xs[tcol8 + 7][trow] = xb.w;
        *(float4*)&Ws[wk][wc4] = wg;
        *(float4*)&Ws[wk][16 + wc4] = wf;
#pragma unroll
        for (int p = 0; p < 4; p++) *(float4*)&Ws[wk][32 + wq * 16 + p * 4] = w1[p];
        __syncthreads();

#pragma unroll 4
        for (int kk = 0; kk < 64; kk++) {
            const f32x2 xv = *(const f32x2*)&xs[kk][ty * 2];
            const f32x2 w01 = *(const f32x2*)&Ws[kk][cg * 6];
            const f32x2 w23 = *(const f32x2*)&Ws[kk][cg * 6 + 2];
            const f32x2 w45 = *(const f32x2*)&Ws[kk][cg * 6 + 4];
            acc[0] += xv * (f32x2){w01[0], w01[0]};
            acc[1] += xv * (f32x2){w01[1], w01[1]};
            acc[2] += xv * (f32x2){w23[0], w23[0]};
            acc[3] += xv * (f32x2){w23[1], w23[1]};
            acc[4] += xv * (f32x2){w45[0], w45[0]};
            acc[5] += xv * (f32x2){w45[1], w45[1]};
        }
    }

#pragma unroll
    for (int j = 0; j < 6; j++) {
        const int c = cg * 6 + j;
#pragma unroll
        for (int r = 0; r < 2; r++) {
            const int gr = row0 + ty * 2 + r;
            const float val = acc[j][r];
            if (c < 16)      graw[(size_t)gr * 16 + c] = val;
            else if (c < 32) fraw[(size_t)gr * 16 + (c - 16)] = val;
            else             g1[(size_t)gr * 64 + (c - 32)] = val;
        }
    }
}

// ---------------------------------------------------------------------------
// Post-projection elementwise. One wave per (row, head). (unchanged)
// ---------------------------------------------------------------------------
__global__ __launch_bounds__(256) void prep_kernel(float* qb, float* kb, float* vb,
                                                   const float* __restrict__ fraw,
                                                   const float* __restrict__ graw,
                                                   float* lfb, float* csb) {
    const int tid = threadIdx.x;
    const int wav = tid >> 6, lane = tid & 63;
    const int gid = blockIdx.x * 4 + wav;  // (r,h)
    const int r = gid >> 4, h = gid & 15;
    const size_t idx = (size_t)r * DD + (size_t)h * HD + lane;

    float xq = qb[idx], xk = kb[idx], xv = vb[idx];
    float q = xq * sigmoidf_(xq);
    float v = xv * sigmoidf_(xv);
    float kk = xk * sigmoidf_(xk);
    float ss = kk * kk;
#pragma unroll
    for (int m = 1; m <= 32; m <<= 1) ss += __shfl_xor(ss, m);
    float norm = fmaxf(sqrtf(ss), 1e-12f);
    float kn = kk / norm;

    float f = fraw[(size_t)r * HH + h];
    float sig = sigmoidf_(f);                               // lambda
    float gm = -sigmoidf_(graw[(size_t)r * HH + h]);        // gamma

    qb[idx] = q;
    vb[idx] = v;
    kb[idx] = kn;
    if (lane == 0) {
        lfb[(size_t)r * HH + h] = sig;
        csb[(size_t)r * HH + h] = gm * sig * sig;
    }
}

// ---------------------------------------------------------------------------
// Chunked delta-rule, phase 1 (fully parallel over all (bh, chunk)):
// per chunk of T=32 steps, with Lam_t = prod lambda (inclusive), c_t = gamma*l^2:
//   khat_t = c_t*Lam_{t-1}*k_t ; kbar_t = k_t/Lam_t ; qtil_t = Lam_t*q_t
//   A = strict_tril(Khat @ KbarT)   (feedback matrix)
//   M = (I - A)^-1                  (fp32 forward substitution)
//   G = tril(Qtil @ KbarT)          (output mixing, incl. diagonal)
// Writes bf16 row-major: Khat,Qtil (32x64), KbarT (64x32), M,G (32x32), LamT.
// One wave per (bh,chunk): 2048 blocks x 64.
// ---------------------------------------------------------------------------
__global__ __launch_bounds__(64) void chunk_prep(const float* __restrict__ qb,
                                                 const float* __restrict__ kb,
                                                 const float* __restrict__ lfb,
                                                 const float* __restrict__ csb,
                                                 __bf16* __restrict__ ck_hat,
                                                 __bf16* __restrict__ ck_q,
                                                 __bf16* __restrict__ ck_kbT,
                                                 __bf16* __restrict__ ck_M,
                                                 __bf16* __restrict__ ck_G,
                                                 float* __restrict__ ck_lam) {
    __shared__ __align__(16) __bf16 khL[32][72];
    __shared__ __align__(16) __bf16 kbL[32][72];
    __shared__ __align__(16) __bf16 qtL[32][72];
    __shared__ float Afp[32][33];
    __shared__ float scl[3][32];
    const int bx = blockIdx.x;
    const int bh = bx >> 6, ci = bx & 63;
    const int b = bh >> 4, h = bh & 15;
    const int l = threadIdx.x;
    const int l15 = l & 15, quad = l >> 4, t32 = l & 31;
    const size_t cid = (size_t)bh * NC + ci;

    // --- lambda cumulative products (both wave halves duplicate t=0..31) ---
    const size_t mb = ((size_t)(b * NN + ci * CT) + t32) * HH + h;
    float c_t = csb[mb];
    float p = lfb[mb];
#pragma unroll
    for (int d = 1; d <= 16; d <<= 1) {
        float o = __shfl_up(p, d);
        p *= (t32 >= d) ? o : 1.f;
    }
    float pm1 = __shfl_up(p, 1);
    if (t32 == 0) pm1 = 1.f;
    const float lamT = __shfl(p, 31);
    if (l < 32) {
        scl[0][t32] = c_t * pm1;  // khat scale
        scl[1][t32] = 1.f / p;    // kbar scale
        scl[2][t32] = p;          // qtil scale
    }
    if (l == 0) ck_lam[cid] = lamT;
    __syncthreads();  // 1-wave block: cheap; orders scl writes vs reads

    // --- scale rows, convert bf16, stage LDS + global ---
    const size_t rb0 = ((size_t)(b * NN + ci * CT)) * DD + h * HD;
    __bf16* khG = ck_hat + cid * 2048;
    __bf16* qtG = ck_q + cid * 2048;
    __bf16* kTG = ck_kbT + cid * 2048;
#pragma unroll
    for (int rep = 0; rep < 8; rep++) {
        const int row = rep * 4 + quad;
        const int c4 = l15 * 4;
        float4 kv = *(const float4*)(kb + rb0 + (size_t)row * DD + c4);
        float4 qv = *(const float4*)(qb + rb0 + (size_t)row * DD + c4);
        const float sh = scl[0][row], sbr = scl[1][row], sq = scl[2][row];
        bf16x4 khv, kbv, qtv;
        khv[0] = (__bf16)(kv.x * sh); khv[1] = (__bf16)(kv.y * sh);
        khv[2] = (__bf16)(kv.z * sh); khv[3] = (__bf16)(kv.w * sh);
        kbv[0] = (__bf16)(kv.x * sbr); kbv[1] = (__bf16)(kv.y * sbr);
        kbv[2] = (__bf16)(kv.z * sbr); kbv[3] = (__bf16)(kv.w * sbr);
        qtv[0] = (__bf16)(qv.x * sq); qtv[1] = (__bf16)(qv.y * sq);
        qtv[2] = (__bf16)(qv.z * sq); qtv[3] = (__bf16)(qv.w * sq);
        *(bf16x4*)&khL[row][c4] = khv;
        *(bf16x4*)&kbL[row][c4] = kbv;
        *(bf16x4*)&qtL[row][c4] = qtv;
        *(bf16x4*)(khG + row * 64 + c4) = khv;
        *(bf16x4*)(qtG + row * 64 + c4) = qtv;
#pragma unroll
        for (int j = 0; j < 4; j++) kTG[(c4 + j) * 32 + row] = kbv[j];
    }
    __syncthreads();

    // --- A = strict_tril(Khat@KbarT), G = tril(Qtil@KbarT) via MFMA ---
    __bf16* GG = ck_G + cid * 1024;
#pragma unroll
    for (int mi = 0; mi < 2; mi++)
#pragma unroll
        for (int ni = 0; ni < 2; ni++) {
            f32x4 aA = (f32x4){0.f, 0.f, 0.f, 0.f};
            f32x4 aG = (f32x4){0.f, 0.f, 0.f, 0.f};
#pragma unroll
            for (int k2 = 0; k2 < 2; k2++) {
                bf16x8 bfr = *(const bf16x8*)&kbL[ni * 16 + l15][k2 * 32 + quad * 8];
                bf16x8 afr = *(const bf16x8*)&khL[mi * 16 + l15][k2 * 32 + quad * 8];
                bf16x8 qfr = *(const bf16x8*)&qtL[mi * 16 + l15][k2 * 32 + quad * 8];
                aA = MFMA16(afr, bfr, aA);
                aG = MFMA16(qfr, bfr, aG);
            }
#pragma unroll
            for (int r = 0; r < 4; r++) {
                const int row = mi * 16 + quad * 4 + r, col = ni * 16 + l15;
                Afp[row][col] = (col < row) ? aA[r] : 0.f;
                GG[row * 32 + col] = (__bf16)((col <= row) ? aG[r] : 0.f);
            }
        }
    __syncthreads();

    // --- M = (I-A)^-1, fp32 forward substitution; lane = column ---
    __bf16* MG = ck_M + cid * 1024;
    if (l < 32) {
        float m[32];
#pragma unroll
        for (int t = 0; t < 32; t++) {
            float r = (l == t) ? 1.f : 0.f;
#pragma unroll
            for (int s = 0; s < t; s++) r += Afp[t][s] * m[s];
            m[t] = r;
            MG[t * 32 + l] = (__bf16)r;
        }
    }
}

// ---------------------------------------------------------------------------
// Chunked delta-rule, phase 2 (serial over 64 chunks; parallel over 32 bh x
// 4 v-slices = 128 waves). State S (64d x 16v) in MFMA D-frag registers.
// Per chunk: P = Khat@S0 ; U = M@(P+V) ; O = Qtil@S0 + G@U ;
//            S = LamT*(S0 + KbarT@U). All matmuls = 16x16x32 bf16 MFMA.
// Next-chunk operand fragments double-buffered in registers.
// ---------------------------------------------------------------------------
struct FragSet {
    bf16x8 ka[2][2], qa[2][2], ma[2], ga[2], kba[4];
    f32x4 vv[2];
    float lam;
};

__global__ __launch_bounds__(64) void chunk_scan(const __bf16* __restrict__ ck_hat,
                                                 const __bf16* __restrict__ ck_q,
                                                 const __bf16* __restrict__ ck_kbT,
                                                 const __bf16* __restrict__ ck_M,
                                                 const __bf16* __restrict__ ck_G,
                                                 const float* __restrict__ ck_lam,
                                                 const float* __restrict__ vb,
                                                 __bf16* __restrict__ obh) {
    __shared__ __align__(16) __bf16 Sbt[16][72];  // [v][d] bf16 S0 for B-frags
    __shared__ __align__(16) __bf16 Vbt[16][40];  // [v][t] V''
    __shared__ __align__(16) __bf16 Ubt[16][40];  // [v][t] U
    const int bx = blockIdx.x;
    const int bh = bx >> 2, vs = bx & 3;
    const int b = bh >> 4, h = bh & 15;
    const int l = threadIdx.x, l15 = l & 15, quad = l >> 4;
    const size_t cid0 = (size_t)bh * NC;
    const size_t vcol = (size_t)h * HD + vs * 16 + l15;
    const size_t rowb = (size_t)b * NN;

    f32x4 S[4];
#pragma unroll
    for (int dt = 0; dt < 4; dt++) S[dt] = (f32x4){0.f, 0.f, 0.f, 0.f};

    auto load = [&](FragSet& f, int ci) {
        const __bf16* khp = ck_hat + (cid0 + ci) * 2048;
        const __bf16* qp = ck_q + (cid0 + ci) * 2048;
        const __bf16* kTp = ck_kbT + (cid0 + ci) * 2048;
        const __bf16* Mp = ck_M + (cid0 + ci) * 1024;
        const __bf16* Gp = ck_G + (cid0 + ci) * 1024;
#pragma unroll
        for (int mi = 0; mi < 2; mi++) {
#pragma unroll
            for (int k2 = 0; k2 < 2; k2++) {
                f.ka[mi][k2] = *(const bf16x8*)(khp + (mi * 16 + l15) * 64 + k2 * 32 + quad * 8);
                f.qa[mi][k2] = *(const bf16x8*)(qp + (mi * 16 + l15) * 64 + k2 * 32 + quad * 8);
            }
            f.ma[mi] = *(const bf16x8*)(Mp + (mi * 16 + l15) * 32 + quad * 8);
            f.ga[mi] = *(const bf16x8*)(Gp + (mi * 16 + l15) * 32 + quad * 8);
        }
#pragma unroll
        for (int dt = 0; dt < 4; dt++)
            f.kba[dt] = *(const bf16x8*)(kTp + (dt * 16 + l15) * 32 + quad * 8);
#pragma unroll
        for (int mi = 0; mi < 2; mi++)
#pragma unroll
            for (int r = 0; r < 4; r++)
                f.vv[mi][r] = vb[(rowb + ci * CT + mi * 16 + quad * 4 + r) * DD + vcol];
        f.lam = ck_lam[cid0 + ci];
    };

    auto compute = [&](const FragSet& f, int ci) {
        const f32x4 z = (f32x4){0.f, 0.f, 0.f, 0.f};
        // S0 -> LDS (bf16, [v][d]) for B-operand fragments
#pragma unroll
        for (int dt = 0; dt < 4; dt++) {
            bf16x4 t;
#pragma unroll
            for (int r = 0; r < 4; r++) t[r] = (__bf16)S[dt][r];
            *(bf16x4*)&Sbt[l15][dt * 16 + quad * 4] = t;
        }
        bf16x8 sb0 = *(const bf16x8*)&Sbt[l15][quad * 8];
        bf16x8 sb1 = *(const bf16x8*)&Sbt[l15][32 + quad * 8];
        // P = Khat @ S0 ; V'' = P + V
        f32x4 p0 = MFMA16(f.ka[0][0], sb0, z); p0 = MFMA16(f.ka[0][1], sb1, p0);
        f32x4 p1 = MFMA16(f.ka[1][0], sb0, z); p1 = MFMA16(f.ka[1][1], sb1, p1);
        p0 += f.vv[0]; p1 += f.vv[1];
        bf16x4 t0, t1;
#pragma unroll
        for (int r = 0; r < 4; r++) { t0[r] = (__bf16)p0[r]; t1[r] = (__bf16)p1[r]; }
        *(bf16x4*)&Vbt[l15][quad * 4] = t0;
        *(bf16x4*)&Vbt[l15][16 + quad * 4] = t1;
        bf16x8 vfr = *(const bf16x8*)&Vbt[l15][quad * 8];
        // U = M @ V''
        f32x4 u0 = MFMA16(f.ma[0], vfr, z);
        f32x4 u1 = MFMA16(f.ma[1], vfr, z);
#pragma unroll
        for (int r = 0; r < 4; r++) { t0[r] = (__bf16)u0[r]; t1[r] = (__bf16)u1[r]; }
        *(bf16x4*)&Ubt[l15][quad * 4] = t0;
        *(bf16x4*)&Ubt[l15][16 + quad * 4] = t1;
        bf16x8 ufr = *(const bf16x8*)&Ubt[l15][quad * 8];
        // O = Qtil @ S0 + G @ U
        f32x4 o0 = MFMA16(f.qa[0][0], sb0, z); o0 = MFMA16(f.qa[0][1], sb1, o0);
        o0 = MFMA16(f.ga[0], ufr, o0);
        f32x4 o1 = MFMA16(f.qa[1][0], sb0, z); o1 = MFMA16(f.qa[1][1], sb1, o1);
        o1 = MFMA16(f.ga[1], ufr, o1);
#pragma unroll
        for (int r = 0; r < 4; r++) {
            obh[(rowb + ci * CT + quad * 4 + r) * DD + vcol] = (__bf16)o0[r];
            obh[(rowb + ci * CT + 16 + quad * 4 + r) * DD + vcol] = (__bf16)o1[r];
        }
        // S = LamT * (S0 + KbarT @ U)
#pragma unroll
        for (int dt = 0; dt < 4; dt++) {
            S[dt] = MFMA16(f.kba[dt], ufr, S[dt]);
#pragma unroll
            for (int r = 0; r < 4; r++) S[dt][r] *= f.lam;
        }
    };

    FragSet fA, fB;
    load(fA, 0);
    for (int ci = 0; ci < NC; ci += 2) {
        load(fB, ci + 1);
        __builtin_amdgcn_sched_barrier(0);  // keep prefetch ahead of compute
        compute(fA, ci);
        load(fA, (ci + 2 < NC) ? ci + 2 : NC - 1);
        __builtin_amdgcn_sched_barrier(0);
        compute(fB, ci + 1);
    }
}

// ---------------------------------------------------------------------------
// outp = LayerNorm(o * sigmoid(gatep)) * norm_w. o is bf16, result fp32.
// (unchanged)
// ---------------------------------------------------------------------------
__global__ __launch_bounds__(256) void gate_ln_kernel(const __bf16* __restrict__ obh,
                                                      const float* __restrict__ gatep,
                                                      const float* __restrict__ nw,
                                                      float* __restrict__ outp) {
    const int r = blockIdx.x, tid = threadIdx.x;
    const int wav = tid >> 6, lane = tid & 63;
    __shared__ float red[8];
    const size_t rb = (size_t)r * DD;

    float vals[4];
    float s = 0.f;
#pragma unroll
    for (int p = 0; p < 4; p++) {
        const int j = tid + 256 * p;
        float xg = (float)obh[rb + j] * sigmoidf_(gatep[rb + j]);
        vals[p] = xg;
        s += xg;
    }
#pragma unroll
    for (int m = 1; m <= 32; m <<= 1) s += __shfl_xor(s, m);
    if (lane == 0) red[wav] = s;
    __syncthreads();
    const float mu = (red[0] + red[1] + red[2] + red[3]) * (1.f / 1024.f);

    float s2 = 0.f;
#pragma unroll
    for (int p = 0; p < 4; p++) { float d = vals[p] - mu; s2 += d * d; }
#pragma unroll
    for (int m = 1; m <= 32; m <<= 1) s2 += __shfl_xor(s2, m);
    if (lane == 0) red[4 + wav] = s2;
    __syncthreads();
    const float var = (red[4] + red[5] + red[6] + red[7]) * (1.f / 1024.f);
    const float rs = rsqrtf(var + 1e-5f);

#pragma unroll
    for (int p = 0; p < 4; p++) {
        const int j = tid + 256 * p;
        outp[rb + j] = (vals[p] - mu) * rs * nw[j];
    }
}

// ---------------------------------------------------------------------------
extern "C" void kernel_launch(void* const* d_in, const int* in_sizes, int n_in,
                              void* d_out, int out_size, void* d_ws, size_t ws_size,
                              hipStream_t stream) {
    const float* x   = (const float*)d_in[0];
    const float* Wq  = (const float*)d_in[1];
    const float* Wk  = (const float*)d_in[2];
    const float* Wv  = (const float*)d_in[3];
    const float* Wgm = (const float*)d_in[4];  // Wgamma
    const float* Wf  = (const float*)d_in[5];
    const float* Wg1 = (const float*)d_in[6];
    const float* Wg2 = (const float*)d_in[7];
    const float* Wo  = (const float*)d_in[8];
    const float* nw  = (const float*)d_in[9];
    float* out = (float*)d_out;

    float* w = (float*)d_ws;
    float* qb    = w;                   // 4096x1024 f32 (q; later LN output)
    float* kb    = qb + 4194304;
    float* vb    = kb + 4194304;
    float* gatep = vb + 4194304;
    float* fraw  = gatep + 4194304;     // 4096x16
    float* graw  = fraw + 65536;        // 4096x16
    float* g1    = graw + 65536;        // 4096x64
    float* lfb   = g1 + 262144;         // 4096x16 (lambda)
    float* csb   = lfb + 65536;         // 4096x16 (gamma*lambda^2)
    __bf16* obh  = (__bf16*)(csb + 65536);  // 4096x1024 bf16 scan output
    float* cw    = csb + 65536 + 2097152;   // chunk workspace (after obh)
    __bf16* ck_hat = (__bf16*)cw;               // [2048][32][64] bf16
    __bf16* ck_q   = (__bf16*)(cw + 2097152);   // [2048][32][64]
    __bf16* ck_kbT = (__bf16*)(cw + 4194304);   // [2048][64][32]
    __bf16* ck_M   = (__bf16*)(cw + 6291456);   // [2048][32][32]
    __bf16* ck_G   = (__bf16*)(cw + 7340032);   // [2048][32][32]
    float*  ck_lam = cw + 8388608;              // [2048]

    dim3 blk(256);
    // fused q,k,v projections: 24 x-blocks = 3 matrices x 8 col-tiles
    gemm_bf16<<<dim3(24, 32), blk, 0, stream>>>(x, Wq, Wk, Wv, qb, kb, vb, RR, DD, DD);
    proj96<<<128, blk, 0, stream>>>(x, Wgm, Wf, Wg1, graw, fraw, g1);
    gemm_f32<<<dim3(8, 32), blk, 0, stream>>>(g1, Wg2, gatep, RR, DD, HD);
    prep_kernel<<<RR * HH / 4, blk, 0, stream>>>(qb, kb, vb, fraw, graw, lfb, csb);
    chunk_prep<<<32 * NC, 64, 0, stream>>>(qb, kb, lfb, csb,
                                           ck_hat, ck_q, ck_kbT, ck_M, ck_G, ck_lam);
    chunk_scan<<<128, 64, 0, stream>>>(ck_hat, ck_q, ck_kbT, ck_M, ck_G, ck_lam, vb, obh);
    gate_ln_kernel<<<RR, blk, 0, stream>>>(obh, gatep, nw, qb);
    gemm_bf16<<<dim3(8, 32), blk, 0, stream>>>(qb, Wo, Wo, Wo, out, out, out, RR, DD, DD);
}

// Round 5
// 326.401 us; speedup vs baseline: 4.2348x; 1.1108x over previous
//
#include <hip/hip_runtime.h>

#define BB 2
#define NN 2048
#define DD 1024
#define HH 16
#define HD 64
#define RR (BB * NN)  // 4096 rows
#define CT 32         // chunk length (steps)
#define NC (NN / CT)  // 64 chunks per (b,h)

typedef __bf16 bf16x8 __attribute__((ext_vector_type(8)));
typedef __bf16 bf16x4 __attribute__((ext_vector_type(4)));
typedef float f32x4 __attribute__((ext_vector_type(4)));
typedef float f32x2 __attribute__((ext_vector_type(2)));

__device__ __forceinline__ float sigmoidf_(float x) { return 1.f / (1.f + __expf(-x)); }

#define MFMA16(a, b, c) __builtin_amdgcn_mfma_f32_16x16x32_bf16((a), (b), (c), 0, 0, 0)

// ---------------------------------------------------------------------------
// x (f32) -> bf16, 8 elems/thread.
// ---------------------------------------------------------------------------
__global__ __launch_bounds__(256) void xcvt(const float* __restrict__ x,
                                            __bf16* __restrict__ xb) {
    const size_t i = ((size_t)blockIdx.x * 256 + threadIdx.x) * 8;
    float4 a = *(const float4*)(x + i);
    float4 b = *(const float4*)(x + i + 4);
    bf16x8 o;
    o[0] = (__bf16)a.x; o[1] = (__bf16)a.y; o[2] = (__bf16)a.z; o[3] = (__bf16)a.w;
    o[4] = (__bf16)b.x; o[5] = (__bf16)b.y; o[6] = (__bf16)b.z; o[7] = (__bf16)b.w;
    *(bf16x8*)(xb + i) = o;
}

// ---------------------------------------------------------------------------
// Weight transpose+convert: S (f32, [K][N]) -> D (bf16, [N][K]).
// 64x64 tiles via LDS. blockIdx.z selects among 4 matrices.
// ---------------------------------------------------------------------------
__global__ __launch_bounds__(256) void wtrans(const float* S0, const float* S1,
                                              const float* S2, const float* S3,
                                              __bf16* D0, __bf16* D1,
                                              __bf16* D2, __bf16* D3,
                                              int K, int N) {
    __shared__ float t[64][65];
    const int z = blockIdx.z;
    const float* S = (z == 0) ? S0 : ((z == 1) ? S1 : ((z == 2) ? S2 : S3));
    __bf16* D = (z == 0) ? D0 : ((z == 1) ? D1 : ((z == 2) ? D2 : D3));
    const int tid = threadIdx.x;
    const int ti = blockIdx.y * 64;  // k tile
    const int tj = blockIdx.x * 64;  // n tile
    const int r = tid >> 2, c0 = (tid & 3) * 16;
    const float* sp = S + (size_t)(ti + r) * N + tj + c0;
#pragma unroll
    for (int p = 0; p < 4; p++) {
        float4 v = *(const float4*)(sp + 4 * p);
        t[r][c0 + 4 * p + 0] = v.x; t[r][c0 + 4 * p + 1] = v.y;
        t[r][c0 + 4 * p + 2] = v.z; t[r][c0 + 4 * p + 3] = v.w;
    }
    __syncthreads();
    bf16x8 o0, o1;
#pragma unroll
    for (int j = 0; j < 8; j++) o0[j] = (__bf16)t[c0 + j][r];
#pragma unroll
    for (int j = 0; j < 8; j++) o1[j] = (__bf16)t[c0 + 8 + j][r];
    __bf16* dp = D + (size_t)(tj + r) * K + ti + c0;
    *(bf16x8*)dp = o0;
    *(bf16x8*)(dp + 8) = o1;
}

// ---------------------------------------------------------------------------
// bf16 GEMM, pre-converted operands: C[M,N](f32) = A[M,K](bf16) @ BT[N,K]^T.
// Staging = 4 contiguous 16B loads/thread/K-step, zero converts. LDS layout,
// fragment reads, MFMA and C-write byte-identical to the verified kernel.
// Block-selected B/C: grid.x = 8*nmat.
// ---------------------------------------------------------------------------
__global__ __launch_bounds__(256) void gemm_bt(const __bf16* __restrict__ A,
                                               const __bf16* B0, const __bf16* B1,
                                               const __bf16* B2,
                                               float* C0, float* C1, float* C2,
                                               int M, int N, int K) {
    constexpr int LW = 40;
    __shared__ __align__(16) __bf16 As[128 * LW];
    __shared__ __align__(16) __bf16 Bs[128 * LW];
    const int mat = blockIdx.x >> 3;
    const __bf16* B = (mat == 0) ? B0 : ((mat == 1) ? B1 : B2);
    float* C = (mat == 0) ? C0 : ((mat == 1) ? C1 : C2);
    const int tid = threadIdx.x;
    const int lane = tid & 63;
    const int wave = tid >> 6;
    const int wm = (wave >> 1) * 64, wn = (wave & 1) * 64;
    const int bm = blockIdx.y * 128, bn = (blockIdx.x & 7) * 128;
    const int l15 = lane & 15, quad = lane >> 4;

    const int ar = tid >> 1, akc = (tid & 1) * 16;
    const int bcol = tid & 127, bk0 = (tid >> 7) * 16;

    f32x4 acc[4][4];
#pragma unroll
    for (int i = 0; i < 4; i++)
#pragma unroll
        for (int j = 0; j < 4; j++) acc[i][j] = (f32x4){0.f, 0.f, 0.f, 0.f};

    for (int kb = 0; kb < K; kb += 32) {
        const __bf16* ap = A + (size_t)(bm + ar) * K + kb + akc;
        const __bf16* bp = B + (size_t)(bn + bcol) * K + kb + bk0;
        bf16x8 a0 = *(const bf16x8*)(ap);
        bf16x8 a1 = *(const bf16x8*)(ap + 8);
        bf16x8 b0 = *(const bf16x8*)(bp);
        bf16x8 b1 = *(const bf16x8*)(bp + 8);

        __syncthreads();
        *(bf16x8*)&As[ar * LW + akc] = a0;
        *(bf16x8*)&As[ar * LW + akc + 8] = a1;
        *(bf16x8*)&Bs[bcol * LW + bk0] = b0;
        *(bf16x8*)&Bs[bcol * LW + bk0 + 8] = b1;
        __syncthreads();

        bf16x8 af[4], bfr[4];
#pragma unroll
        for (int i = 0; i < 4; i++)
            af[i] = *(const bf16x8*)&As[(wm + i * 16 + l15) * LW + quad * 8];
#pragma unroll
        for (int j = 0; j < 4; j++)
            bfr[j] = *(const bf16x8*)&Bs[(wn + j * 16 + l15) * LW + quad * 8];
#pragma unroll
        for (int i = 0; i < 4; i++)
#pragma unroll
            for (int j = 0; j < 4; j++)
                acc[i][j] = MFMA16(af[i], bfr[j], acc[i][j]);
    }

#pragma unroll
    for (int i = 0; i < 4; i++) {
#pragma unroll
        for (int r = 0; r < 4; r++) {
            const int row = bm + wm + i * 16 + quad * 4 + r;
            float* cp = C + (size_t)row * N + bn + wn + l15;
#pragma unroll
            for (int j = 0; j < 4; j++) cp[j * 16] = acc[i][j][r];
        }
    }
}

// ---------------------------------------------------------------------------
// Fused skinny projections: [graw|fraw|g1b] = x @ [Wgamma|Wf|Wg1] (96 cols).
// 256 blocks x 16 rows (full-CU parallelism). W chunk + transposed x in LDS.
// g1 written bf16 (feeds the bf16 gate GEMM).
// ---------------------------------------------------------------------------
__global__ __launch_bounds__(256) void proj96(const float* __restrict__ x,
                                              const float* __restrict__ Wgm,
                                              const float* __restrict__ Wf,
                                              const float* __restrict__ Wg1,
                                              float* __restrict__ graw,
                                              float* __restrict__ fraw,
                                              __bf16* __restrict__ g1b) {
    __shared__ float xs[64][17];    // [k][row]
    __shared__ float Ws[64][100];   // [k][col], 96->100 pad
    const int tid = threadIdx.x;
    const int row0 = blockIdx.x * 16;
    const int r = tid >> 4;    // 0..15 (row)
    const int cg = tid & 15;   // cols cg*6..cg*6+5

    const int trow = tid >> 4, tc4 = (tid & 15) * 4;  // x staging
    const int wk = tid >> 2;                          // W row 0..63
    const int wc4 = (tid & 3) * 4;
    const int wq = tid & 3;

    float acc[6] = {0.f, 0.f, 0.f, 0.f, 0.f, 0.f};

    for (int kc = 0; kc < DD; kc += 64) {
        float4 xa = *(const float4*)(x + (size_t)(row0 + trow) * DD + kc + tc4);
        float4 wg = *(const float4*)(Wgm + (size_t)(kc + wk) * 16 + wc4);
        float4 wf = *(const float4*)(Wf + (size_t)(kc + wk) * 16 + wc4);
        float4 w1[4];
#pragma unroll
        for (int p = 0; p < 4; p++)
            w1[p] = *(const float4*)(Wg1 + (size_t)(kc + wk) * 64 + wq * 16 + p * 4);

        __syncthreads();
        xs[tc4 + 0][trow] = xa.x; xs[tc4 + 1][trow] = xa.y;
        xs[tc4 + 2][trow] = xa.z; xs[tc4 + 3][trow] = xa.w;
        *(float4*)&Ws[wk][wc4] = wg;
        *(float4*)&Ws[wk][16 + wc4] = wf;
#pragma unroll
        for (int p = 0; p < 4; p++) *(float4*)&Ws[wk][32 + wq * 16 + p * 4] = w1[p];
        __syncthreads();

#pragma unroll 4
        for (int kk = 0; kk < 64; kk++) {
            const float xv = xs[kk][r];
            const f32x2 w01 = *(const f32x2*)&Ws[kk][cg * 6];
            const f32x2 w23 = *(const f32x2*)&Ws[kk][cg * 6 + 2];
            const f32x2 w45 = *(const f32x2*)&Ws[kk][cg * 6 + 4];
            acc[0] += xv * w01[0]; acc[1] += xv * w01[1];
            acc[2] += xv * w23[0]; acc[3] += xv * w23[1];
            acc[4] += xv * w45[0]; acc[5] += xv * w45[1];
        }
    }

    const int gr = row0 + r;
#pragma unroll
    for (int j = 0; j < 6; j++) {
        const int c = cg * 6 + j;
        if (c < 16)      graw[(size_t)gr * 16 + c] = acc[j];
        else if (c < 32) fraw[(size_t)gr * 16 + (c - 16)] = acc[j];
        else             g1b[(size_t)gr * 64 + (c - 32)] = (__bf16)acc[j];
    }
}

// ---------------------------------------------------------------------------
// Post-projection elementwise. One wave per (row, head). (unchanged)
// ---------------------------------------------------------------------------
__global__ __launch_bounds__(256) void prep_kernel(float* qb, float* kb, float* vb,
                                                   const float* __restrict__ fraw,
                                                   const float* __restrict__ graw,
                                                   float* lfb, float* csb) {
    const int tid = threadIdx.x;
    const int wav = tid >> 6, lane = tid & 63;
    const int gid = blockIdx.x * 4 + wav;  // (r,h)
    const int r = gid >> 4, h = gid & 15;
    const size_t idx = (size_t)r * DD + (size_t)h * HD + lane;

    float xq = qb[idx], xk = kb[idx], xv = vb[idx];
    float q = xq * sigmoidf_(xq);
    float v = xv * sigmoidf_(xv);
    float kk = xk * sigmoidf_(xk);
    float ss = kk * kk;
#pragma unroll
    for (int m = 1; m <= 32; m <<= 1) ss += __shfl_xor(ss, m);
    float norm = fmaxf(sqrtf(ss), 1e-12f);
    float kn = kk / norm;

    float f = fraw[(size_t)r * HH + h];
    float sig = sigmoidf_(f);                               // lambda
    float gm = -sigmoidf_(graw[(size_t)r * HH + h]);        // gamma

    qb[idx] = q;
    vb[idx] = v;
    kb[idx] = kn;
    if (lane == 0) {
        lfb[(size_t)r * HH + h] = sig;
        csb[(size_t)r * HH + h] = gm * sig * sig;
    }
}

// ---------------------------------------------------------------------------
// Chunked delta-rule, phase 1. (unchanged — verified round 4)
// ---------------------------------------------------------------------------
__global__ __launch_bounds__(64) void chunk_prep(const float* __restrict__ qb,
                                                 const float* __restrict__ kb,
                                                 const float* __restrict__ lfb,
                                                 const float* __restrict__ csb,
                                                 __bf16* __restrict__ ck_hat,
                                                 __bf16* __restrict__ ck_q,
                                                 __bf16* __restrict__ ck_kbT,
                                                 __bf16* __restrict__ ck_M,
                                                 __bf16* __restrict__ ck_G,
                                                 float* __restrict__ ck_lam) {
    __shared__ __align__(16) __bf16 khL[32][72];
    __shared__ __align__(16) __bf16 kbL[32][72];
    __shared__ __align__(16) __bf16 qtL[32][72];
    __shared__ float Afp[32][33];
    __shared__ float scl[3][32];
    const int bx = blockIdx.x;
    const int bh = bx >> 6, ci = bx & 63;
    const int b = bh >> 4, h = bh & 15;
    const int l = threadIdx.x;
    const int l15 = l & 15, quad = l >> 4, t32 = l & 31;
    const size_t cid = (size_t)bh * NC + ci;

    const size_t mb = ((size_t)(b * NN + ci * CT) + t32) * HH + h;
    float c_t = csb[mb];
    float p = lfb[mb];
#pragma unroll
    for (int d = 1; d <= 16; d <<= 1) {
        float o = __shfl_up(p, d);
        p *= (t32 >= d) ? o : 1.f;
    }
    float pm1 = __shfl_up(p, 1);
    if (t32 == 0) pm1 = 1.f;
    const float lamT = __shfl(p, 31);
    if (l < 32) {
        scl[0][t32] = c_t * pm1;  // khat scale
        scl[1][t32] = 1.f / p;    // kbar scale
        scl[2][t32] = p;          // qtil scale
    }
    if (l == 0) ck_lam[cid] = lamT;
    __syncthreads();

    const size_t rb0 = ((size_t)(b * NN + ci * CT)) * DD + h * HD;
    __bf16* khG = ck_hat + cid * 2048;
    __bf16* qtG = ck_q + cid * 2048;
    __bf16* kTG = ck_kbT + cid * 2048;
#pragma unroll
    for (int rep = 0; rep < 8; rep++) {
        const int row = rep * 4 + quad;
        const int c4 = l15 * 4;
        float4 kv = *(const float4*)(kb + rb0 + (size_t)row * DD + c4);
        float4 qv = *(const float4*)(qb + rb0 + (size_t)row * DD + c4);
        const float sh = scl[0][row], sbr = scl[1][row], sq = scl[2][row];
        bf16x4 khv, kbv, qtv;
        khv[0] = (__bf16)(kv.x * sh); khv[1] = (__bf16)(kv.y * sh);
        khv[2] = (__bf16)(kv.z * sh); khv[3] = (__bf16)(kv.w * sh);
        kbv[0] = (__bf16)(kv.x * sbr); kbv[1] = (__bf16)(kv.y * sbr);
        kbv[2] = (__bf16)(kv.z * sbr); kbv[3] = (__bf16)(kv.w * sbr);
        qtv[0] = (__bf16)(qv.x * sq); qtv[1] = (__bf16)(qv.y * sq);
        qtv[2] = (__bf16)(qv.z * sq); qtv[3] = (__bf16)(qv.w * sq);
        *(bf16x4*)&khL[row][c4] = khv;
        *(bf16x4*)&kbL[row][c4] = kbv;
        *(bf16x4*)&qtL[row][c4] = qtv;
        *(bf16x4*)(khG + row * 64 + c4) = khv;
        *(bf16x4*)(qtG + row * 64 + c4) = qtv;
#pragma unroll
        for (int j = 0; j < 4; j++) kTG[(c4 + j) * 32 + row] = kbv[j];
    }
    __syncthreads();

    __bf16* GG = ck_G + cid * 1024;
#pragma unroll
    for (int mi = 0; mi < 2; mi++)
#pragma unroll
        for (int ni = 0; ni < 2; ni++) {
            f32x4 aA = (f32x4){0.f, 0.f, 0.f, 0.f};
            f32x4 aG = (f32x4){0.f, 0.f, 0.f, 0.f};
#pragma unroll
            for (int k2 = 0; k2 < 2; k2++) {
                bf16x8 bfr = *(const bf16x8*)&kbL[ni * 16 + l15][k2 * 32 + quad * 8];
                bf16x8 afr = *(const bf16x8*)&khL[mi * 16 + l15][k2 * 32 + quad * 8];
                bf16x8 qfr = *(const bf16x8*)&qtL[mi * 16 + l15][k2 * 32 + quad * 8];
                aA = MFMA16(afr, bfr, aA);
                aG = MFMA16(qfr, bfr, aG);
            }
#pragma unroll
            for (int r = 0; r < 4; r++) {
                const int row = mi * 16 + quad * 4 + r, col = ni * 16 + l15;
                Afp[row][col] = (col < row) ? aA[r] : 0.f;
                GG[row * 32 + col] = (__bf16)((col <= row) ? aG[r] : 0.f);
            }
        }
    __syncthreads();

    __bf16* MG = ck_M + cid * 1024;
    if (l < 32) {
        float m[32];
#pragma unroll
        for (int t = 0; t < 32; t++) {
            float r = (l == t) ? 1.f : 0.f;
#pragma unroll
            for (int s = 0; s < t; s++) r += Afp[t][s] * m[s];
            m[t] = r;
            MG[t * 32 + l] = (__bf16)r;
        }
    }
}

// ---------------------------------------------------------------------------
// Chunked delta-rule, phase 2. (unchanged — verified round 4)
// ---------------------------------------------------------------------------
struct FragSet {
    bf16x8 ka[2][2], qa[2][2], ma[2], ga[2], kba[4];
    f32x4 vv[2];
    float lam;
};

__global__ __launch_bounds__(64) void chunk_scan(const __bf16* __restrict__ ck_hat,
                                                 const __bf16* __restrict__ ck_q,
                                                 const __bf16* __restrict__ ck_kbT,
                                                 const __bf16* __restrict__ ck_M,
                                                 const __bf16* __restrict__ ck_G,
                                                 const float* __restrict__ ck_lam,
                                                 const float* __restrict__ vb,
                                                 __bf16* __restrict__ obh) {
    __shared__ __align__(16) __bf16 Sbt[16][72];
    __shared__ __align__(16) __bf16 Vbt[16][40];
    __shared__ __align__(16) __bf16 Ubt[16][40];
    const int bx = blockIdx.x;
    const int bh = bx >> 2, vs = bx & 3;
    const int b = bh >> 4, h = bh & 15;
    const int l = threadIdx.x, l15 = l & 15, quad = l >> 4;
    const size_t cid0 = (size_t)bh * NC;
    const size_t vcol = (size_t)h * HD + vs * 16 + l15;
    const size_t rowb = (size_t)b * NN;

    f32x4 S[4];
#pragma unroll
    for (int dt = 0; dt < 4; dt++) S[dt] = (f32x4){0.f, 0.f, 0.f, 0.f};

    auto load = [&](FragSet& f, int ci) {
        const __bf16* khp = ck_hat + (cid0 + ci) * 2048;
        const __bf16* qp = ck_q + (cid0 + ci) * 2048;
        const __bf16* kTp = ck_kbT + (cid0 + ci) * 2048;
        const __bf16* Mp = ck_M + (cid0 + ci) * 1024;
        const __bf16* Gp = ck_G + (cid0 + ci) * 1024;
#pragma unroll
        for (int mi = 0; mi < 2; mi++) {
#pragma unroll
            for (int k2 = 0; k2 < 2; k2++) {
                f.ka[mi][k2] = *(const bf16x8*)(khp + (mi * 16 + l15) * 64 + k2 * 32 + quad * 8);
                f.qa[mi][k2] = *(const bf16x8*)(qp + (mi * 16 + l15) * 64 + k2 * 32 + quad * 8);
            }
            f.ma[mi] = *(const bf16x8*)(Mp + (mi * 16 + l15) * 32 + quad * 8);
            f.ga[mi] = *(const bf16x8*)(Gp + (mi * 16 + l15) * 32 + quad * 8);
        }
#pragma unroll
        for (int dt = 0; dt < 4; dt++)
            f.kba[dt] = *(const bf16x8*)(kTp + (dt * 16 + l15) * 32 + quad * 8);
#pragma unroll
        for (int mi = 0; mi < 2; mi++)
#pragma unroll
            for (int r = 0; r < 4; r++)
                f.vv[mi][r] = vb[(rowb + ci * CT + mi * 16 + quad * 4 + r) * DD + vcol];
        f.lam = ck_lam[cid0 + ci];
    };

    auto compute = [&](const FragSet& f, int ci) {
        const f32x4 z = (f32x4){0.f, 0.f, 0.f, 0.f};
#pragma unroll
        for (int dt = 0; dt < 4; dt++) {
            bf16x4 t;
#pragma unroll
            for (int r = 0; r < 4; r++) t[r] = (__bf16)S[dt][r];
            *(bf16x4*)&Sbt[l15][dt * 16 + quad * 4] = t;
        }
        bf16x8 sb0 = *(const bf16x8*)&Sbt[l15][quad * 8];
        bf16x8 sb1 = *(const bf16x8*)&Sbt[l15][32 + quad * 8];
        f32x4 p0 = MFMA16(f.ka[0][0], sb0, z); p0 = MFMA16(f.ka[0][1], sb1, p0);
        f32x4 p1 = MFMA16(f.ka[1][0], sb0, z); p1 = MFMA16(f.ka[1][1], sb1, p1);
        p0 += f.vv[0]; p1 += f.vv[1];
        bf16x4 t0, t1;
#pragma unroll
        for (int r = 0; r < 4; r++) { t0[r] = (__bf16)p0[r]; t1[r] = (__bf16)p1[r]; }
        *(bf16x4*)&Vbt[l15][quad * 4] = t0;
        *(bf16x4*)&Vbt[l15][16 + quad * 4] = t1;
        bf16x8 vfr = *(const bf16x8*)&Vbt[l15][quad * 8];
        f32x4 u0 = MFMA16(f.ma[0], vfr, z);
        f32x4 u1 = MFMA16(f.ma[1], vfr, z);
#pragma unroll
        for (int r = 0; r < 4; r++) { t0[r] = (__bf16)u0[r]; t1[r] = (__bf16)u1[r]; }
        *(bf16x4*)&Ubt[l15][quad * 4] = t0;
        *(bf16x4*)&Ubt[l15][16 + quad * 4] = t1;
        bf16x8 ufr = *(const bf16x8*)&Ubt[l15][quad * 8];
        f32x4 o0 = MFMA16(f.qa[0][0], sb0, z); o0 = MFMA16(f.qa[0][1], sb1, o0);
        o0 = MFMA16(f.ga[0], ufr, o0);
        f32x4 o1 = MFMA16(f.qa[1][0], sb0, z); o1 = MFMA16(f.qa[1][1], sb1, o1);
        o1 = MFMA16(f.ga[1], ufr, o1);
#pragma unroll
        for (int r = 0; r < 4; r++) {
            obh[(rowb + ci * CT + quad * 4 + r) * DD + vcol] = (__bf16)o0[r];
            obh[(rowb + ci * CT + 16 + quad * 4 + r) * DD + vcol] = (__bf16)o1[r];
        }
#pragma unroll
        for (int dt = 0; dt < 4; dt++) {
            S[dt] = MFMA16(f.kba[dt], ufr, S[dt]);
#pragma unroll
            for (int r = 0; r < 4; r++) S[dt][r] *= f.lam;
        }
    };

    FragSet fA, fB;
    load(fA, 0);
    for (int ci = 0; ci < NC; ci += 2) {
        load(fB, ci + 1);
        __builtin_amdgcn_sched_barrier(0);
        compute(fA, ci);
        load(fA, (ci + 2 < NC) ? ci + 2 : NC - 1);
        __builtin_amdgcn_sched_barrier(0);
        compute(fB, ci + 1);
    }
}

// ---------------------------------------------------------------------------
// lnob = bf16( LayerNorm(o * sigmoid(gatep)) * norm_w ).
// ---------------------------------------------------------------------------
__global__ __launch_bounds__(256) void gate_ln_kernel(const __bf16* __restrict__ obh,
                                                      const float* __restrict__ gatep,
                                                      const float* __restrict__ nw,
                                                      __bf16* __restrict__ lnob) {
    const int r = blockIdx.x, tid = threadIdx.x;
    const int wav = tid >> 6, lane = tid & 63;
    __shared__ float red[8];
    const size_t rb = (size_t)r * DD;

    float vals[4];
    float s = 0.f;
#pragma unroll
    for (int p = 0; p < 4; p++) {
        const int j = tid + 256 * p;
        float xg = (float)obh[rb + j] * sigmoidf_(gatep[rb + j]);
        vals[p] = xg;
        s += xg;
    }
#pragma unroll
    for (int m = 1; m <= 32; m <<= 1) s += __shfl_xor(s, m);
    if (lane == 0) red[wav] = s;
    __syncthreads();
    const float mu = (red[0] + red[1] + red[2] + red[3]) * (1.f / 1024.f);

    float s2 = 0.f;
#pragma unroll
    for (int p = 0; p < 4; p++) { float d = vals[p] - mu; s2 += d * d; }
#pragma unroll
    for (int m = 1; m <= 32; m <<= 1) s2 += __shfl_xor(s2, m);
    if (lane == 0) red[4 + wav] = s2;
    __syncthreads();
    const float var = (red[4] + red[5] + red[6] + red[7]) * (1.f / 1024.f);
    const float rs = rsqrtf(var + 1e-5f);

#pragma unroll
    for (int p = 0; p < 4; p++) {
        const int j = tid + 256 * p;
        lnob[rb + j] = (__bf16)((vals[p] - mu) * rs * nw[j]);
    }
}

// ---------------------------------------------------------------------------
extern "C" void kernel_launch(void* const* d_in, const int* in_sizes, int n_in,
                              void* d_out, int out_size, void* d_ws, size_t ws_size,
                              hipStream_t stream) {
    const float* x   = (const float*)d_in[0];
    const float* Wq  = (const float*)d_in[1];
    const float* Wk  = (const float*)d_in[2];
    const float* Wv  = (const float*)d_in[3];
    const float* Wgm = (const float*)d_in[4];  // Wgamma
    const float* Wf  = (const float*)d_in[5];
    const float* Wg1 = (const float*)d_in[6];
    const float* Wg2 = (const float*)d_in[7];
    const float* Wo  = (const float*)d_in[8];
    const float* nw  = (const float*)d_in[9];
    float* out = (float*)d_out;

    float* w = (float*)d_ws;
    float* qb    = w;                   // 4096x1024 f32 (later reused as lnob bf16)
    float* kb    = qb + 4194304;
    float* vb    = kb + 4194304;
    float* gatep = vb + 4194304;
    float* fraw  = gatep + 4194304;     // 4096x16
    float* graw  = fraw + 65536;        // 4096x16
    __bf16* g1b  = (__bf16*)(graw + 65536);   // 4096x64 bf16 (in old g1 slot)
    float* lfb   = graw + 65536 + 262144;     // 4096x16 (lambda)
    float* csb   = lfb + 65536;               // 4096x16 (gamma*lambda^2)
    __bf16* obh  = (__bf16*)(csb + 65536);    // 4096x1024 bf16 scan output
    float* cw    = csb + 65536 + 2097152;     // chunk workspace
    __bf16* ck_hat = (__bf16*)cw;               // [2048][32][64] bf16
    __bf16* ck_q   = (__bf16*)(cw + 2097152);   // [2048][32][64]
    __bf16* ck_kbT = (__bf16*)(cw + 4194304);   // [2048][64][32]
    __bf16* ck_M   = (__bf16*)(cw + 6291456);   // [2048][32][32]
    __bf16* ck_G   = (__bf16*)(cw + 7340032);   // [2048][32][32]
    float*  ck_lam = cw + 8388608;              // [2048]
    float* nw2   = cw + 8390656;
    __bf16* xb   = (__bf16*)nw2;                // 4096x1024 bf16
    __bf16* WqT  = (__bf16*)(nw2 + 2097152);    // 1024x1024 bf16 (transposed)
    __bf16* WkT  = (__bf16*)(nw2 + 2621440);
    __bf16* WvT  = (__bf16*)(nw2 + 3145728);
    __bf16* WoT  = (__bf16*)(nw2 + 3670016);
    __bf16* Wg2T = (__bf16*)(nw2 + 4194304);    // 1024x64 bf16
    __bf16* lnob = (__bf16*)qb;                 // reuse qb (free after chunk_prep)

    dim3 blk(256);
    xcvt<<<2048, blk, 0, stream>>>(x, xb);
    wtrans<<<dim3(16, 16, 4), blk, 0, stream>>>(Wq, Wk, Wv, Wo, WqT, WkT, WvT, WoT,
                                                DD, DD);
    wtrans<<<dim3(16, 1, 1), blk, 0, stream>>>(Wg2, Wg2, Wg2, Wg2, Wg2T, Wg2T, Wg2T,
                                               Wg2T, HD, DD);
    // fused q,k,v projections: 24 x-blocks = 3 matrices x 8 col-tiles
    gemm_bt<<<dim3(24, 32), blk, 0, stream>>>(xb, WqT, WkT, WvT, qb, kb, vb, RR, DD, DD);
    proj96<<<256, blk, 0, stream>>>(x, Wgm, Wf, Wg1, graw, fraw, g1b);
    gemm_bt<<<dim3(8, 32), blk, 0, stream>>>(g1b, Wg2T, Wg2T, Wg2T, gatep, gatep, gatep,
                                             RR, DD, HD);
    prep_kernel<<<RR * HH / 4, blk, 0, stream>>>(qb, kb, vb, fraw, graw, lfb, csb);
    chunk_prep<<<32 * NC, 64, 0, stream>>>(qb, kb, lfb, csb,
                                           ck_hat, ck_q, ck_kbT, ck_M, ck_G, ck_lam);
    chunk_scan<<<128, 64, 0, stream>>>(ck_hat, ck_q, ck_kbT, ck_M, ck_G, ck_lam, vb, obh);
    gate_ln_kernel<<<RR, blk, 0, stream>>>(obh, gatep, nw, lnob);
    gemm_bt<<<dim3(8, 32), blk, 0, stream>>>(lnob, WoT, WoT, WoT, out, out, out, RR, DD, DD);
}

// Round 6
// 292.598 us; speedup vs baseline: 4.7241x; 1.1155x over previous
//
#include <hip/hip_runtime.h>

#define BB 2
#define NN 2048
#define DD 1024
#define HH 16
#define HD 64
#define RR (BB * NN)  // 4096 rows
#define CT 32         // chunk length (steps)
#define NC (NN / CT)  // 64 chunks per (b,h)

typedef __bf16 bf16x8 __attribute__((ext_vector_type(8)));
typedef __bf16 bf16x4 __attribute__((ext_vector_type(4)));
typedef float f32x4 __attribute__((ext_vector_type(4)));
typedef float f32x2 __attribute__((ext_vector_type(2)));

__device__ __forceinline__ float sigmoidf_(float x) { return 1.f / (1.f + __expf(-x)); }

#define MFMA16(a, b, c) __builtin_amdgcn_mfma_f32_16x16x32_bf16((a), (b), (c), 0, 0, 0)

// ---------------------------------------------------------------------------
// x (f32) -> bf16, 8 elems/thread.
// ---------------------------------------------------------------------------
__global__ __launch_bounds__(256) void xcvt(const float* __restrict__ x,
                                            __bf16* __restrict__ xb) {
    const size_t i = ((size_t)blockIdx.x * 256 + threadIdx.x) * 8;
    float4 a = *(const float4*)(x + i);
    float4 b = *(const float4*)(x + i + 4);
    bf16x8 o;
    o[0] = (__bf16)a.x; o[1] = (__bf16)a.y; o[2] = (__bf16)a.z; o[3] = (__bf16)a.w;
    o[4] = (__bf16)b.x; o[5] = (__bf16)b.y; o[6] = (__bf16)b.z; o[7] = (__bf16)b.w;
    *(bf16x8*)(xb + i) = o;
}

// ---------------------------------------------------------------------------
// Weight transpose+convert: S (f32, [K][N]) -> D (bf16, [N][K]).
// 64x64 tiles via LDS. blockIdx.z selects among 4 matrices. (unchanged)
// ---------------------------------------------------------------------------
__global__ __launch_bounds__(256) void wtrans(const float* S0, const float* S1,
                                              const float* S2, const float* S3,
                                              __bf16* D0, __bf16* D1,
                                              __bf16* D2, __bf16* D3,
                                              int K, int N) {
    __shared__ float t[64][65];
    const int z = blockIdx.z;
    const float* S = (z == 0) ? S0 : ((z == 1) ? S1 : ((z == 2) ? S2 : S3));
    __bf16* D = (z == 0) ? D0 : ((z == 1) ? D1 : ((z == 2) ? D2 : D3));
    const int tid = threadIdx.x;
    const int ti = blockIdx.y * 64;  // k tile
    const int tj = blockIdx.x * 64;  // n tile
    const int r = tid >> 2, c0 = (tid & 3) * 16;
    const float* sp = S + (size_t)(ti + r) * N + tj + c0;
#pragma unroll
    for (int p = 0; p < 4; p++) {
        float4 v = *(const float4*)(sp + 4 * p);
        t[r][c0 + 4 * p + 0] = v.x; t[r][c0 + 4 * p + 1] = v.y;
        t[r][c0 + 4 * p + 2] = v.z; t[r][c0 + 4 * p + 3] = v.w;
    }
    __syncthreads();
    bf16x8 o0, o1;
#pragma unroll
    for (int j = 0; j < 8; j++) o0[j] = (__bf16)t[c0 + j][r];
#pragma unroll
    for (int j = 0; j < 8; j++) o1[j] = (__bf16)t[c0 + 8 + j][r];
    __bf16* dp = D + (size_t)(tj + r) * K + ti + c0;
    *(bf16x8*)dp = o0;
    *(bf16x8*)(dp + 8) = o1;
}

// ---------------------------------------------------------------------------
// W96T[c][k] (bf16, 128x1024, zero-padded rows 96..127) = [Wgamma|Wf|Wg1]^T.
// One block per output row c; thread covers 4 k.
// ---------------------------------------------------------------------------
__global__ __launch_bounds__(256) void wtrans96(const float* __restrict__ Wgm,
                                                const float* __restrict__ Wf,
                                                const float* __restrict__ Wg1,
                                                __bf16* __restrict__ W96T) {
    const int c = blockIdx.x;        // 0..127
    const int k0 = threadIdx.x * 4;  // 0..1020
    bf16x4 o;
    if (c < 96) {
        const float* src;
        int stride;
        if (c < 16)      { src = Wgm + c;        stride = 16; }
        else if (c < 32) { src = Wf + (c - 16);  stride = 16; }
        else             { src = Wg1 + (c - 32); stride = 64; }
#pragma unroll
        for (int j = 0; j < 4; j++) o[j] = (__bf16)src[(size_t)(k0 + j) * stride];
    } else {
        o[0] = o[1] = o[2] = o[3] = (__bf16)0.f;
    }
    *(bf16x4*)(W96T + (size_t)c * 1024 + k0) = o;
}

// ---------------------------------------------------------------------------
// bf16 GEMM, pre-converted operands: C[M,Nn](f32) = A[M,K](bf16) @ BT[Nn,K]^T.
// Block-selected B/C pairs: grid.x = 8*nmat (+1 for the 128-col mat 3).
// mat 3 has Nn=128 (single column tile at bn=0). Body verified.
// ---------------------------------------------------------------------------
__global__ __launch_bounds__(256) void gemm_bt(const __bf16* __restrict__ A,
                                               const __bf16* B0, const __bf16* B1,
                                               const __bf16* B2, const __bf16* B3,
                                               float* C0, float* C1, float* C2, float* C3,
                                               int M, int N, int K) {
    constexpr int LW = 40;
    __shared__ __align__(16) __bf16 As[128 * LW];
    __shared__ __align__(16) __bf16 Bs[128 * LW];
    const int mat = blockIdx.x >> 3;
    const __bf16* B = (mat == 0) ? B0 : ((mat == 1) ? B1 : ((mat == 2) ? B2 : B3));
    float* C = (mat == 0) ? C0 : ((mat == 1) ? C1 : ((mat == 2) ? C2 : C3));
    const int Nn = (mat == 3) ? 128 : N;
    const int tid = threadIdx.x;
    const int lane = tid & 63;
    const int wave = tid >> 6;
    const int wm = (wave >> 1) * 64, wn = (wave & 1) * 64;
    const int bm = blockIdx.y * 128, bn = (blockIdx.x & 7) * 128;
    const int l15 = lane & 15, quad = lane >> 4;

    const int ar = tid >> 1, akc = (tid & 1) * 16;
    const int bcol = tid & 127, bk0 = (tid >> 7) * 16;

    f32x4 acc[4][4];
#pragma unroll
    for (int i = 0; i < 4; i++)
#pragma unroll
        for (int j = 0; j < 4; j++) acc[i][j] = (f32x4){0.f, 0.f, 0.f, 0.f};

    for (int kb = 0; kb < K; kb += 32) {
        const __bf16* ap = A + (size_t)(bm + ar) * K + kb + akc;
        const __bf16* bp = B + (size_t)(bn + bcol) * K + kb + bk0;
        bf16x8 a0 = *(const bf16x8*)(ap);
        bf16x8 a1 = *(const bf16x8*)(ap + 8);
        bf16x8 b0 = *(const bf16x8*)(bp);
        bf16x8 b1 = *(const bf16x8*)(bp + 8);

        __syncthreads();
        *(bf16x8*)&As[ar * LW + akc] = a0;
        *(bf16x8*)&As[ar * LW + akc + 8] = a1;
        *(bf16x8*)&Bs[bcol * LW + bk0] = b0;
        *(bf16x8*)&Bs[bcol * LW + bk0 + 8] = b1;
        __syncthreads();

        bf16x8 af[4], bfr[4];
#pragma unroll
        for (int i = 0; i < 4; i++)
            af[i] = *(const bf16x8*)&As[(wm + i * 16 + l15) * LW + quad * 8];
#pragma unroll
        for (int j = 0; j < 4; j++)
            bfr[j] = *(const bf16x8*)&Bs[(wn + j * 16 + l15) * LW + quad * 8];
#pragma unroll
        for (int i = 0; i < 4; i++)
#pragma unroll
            for (int j = 0; j < 4; j++)
                acc[i][j] = MFMA16(af[i], bfr[j], acc[i][j]);
    }

#pragma unroll
    for (int i = 0; i < 4; i++) {
#pragma unroll
        for (int r = 0; r < 4; r++) {
            const int row = bm + wm + i * 16 + quad * 4 + r;
            float* cp = C + (size_t)row * Nn + bn + wn + l15;
#pragma unroll
            for (int j = 0; j < 4; j++) cp[j * 16] = acc[i][j][r];
        }
    }
}

// ---------------------------------------------------------------------------
// Post-projection elementwise. One wave per (row, head). gamma/f raws read
// from c96 (cols 0..15 / 16..31); h==0 waves also convert the g1 slice
// (cols 32..95) to bf16 for the gate GEMM.
// ---------------------------------------------------------------------------
__global__ __launch_bounds__(256) void prep_kernel(float* qb, float* kb, float* vb,
                                                   const float* __restrict__ c96,
                                                   float* lfb, float* csb,
                                                   __bf16* __restrict__ g1b) {
    const int tid = threadIdx.x;
    const int wav = tid >> 6, lane = tid & 63;
    const int gid = blockIdx.x * 4 + wav;  // (r,h)
    const int r = gid >> 4, h = gid & 15;
    const size_t idx = (size_t)r * DD + (size_t)h * HD + lane;

    float xq = qb[idx], xk = kb[idx], xv = vb[idx];
    float q = xq * sigmoidf_(xq);
    float v = xv * sigmoidf_(xv);
    float kk = xk * sigmoidf_(xk);
    float ss = kk * kk;
#pragma unroll
    for (int m = 1; m <= 32; m <<= 1) ss += __shfl_xor(ss, m);
    float norm = fmaxf(sqrtf(ss), 1e-12f);
    float kn = kk / norm;

    float f = c96[(size_t)r * 128 + 16 + h];
    float sig = sigmoidf_(f);                                  // lambda
    float gm = -sigmoidf_(c96[(size_t)r * 128 + h]);           // gamma

    qb[idx] = q;
    vb[idx] = v;
    kb[idx] = kn;
    if (lane == 0) {
        lfb[(size_t)r * HH + h] = sig;
        csb[(size_t)r * HH + h] = gm * sig * sig;
    }
    if (h == 0) g1b[(size_t)r * 64 + lane] = (__bf16)c96[(size_t)r * 128 + 32 + lane];
}

// ---------------------------------------------------------------------------
// Chunked delta-rule, phase 1. (unchanged — verified round 4)
// ---------------------------------------------------------------------------
__global__ __launch_bounds__(64) void chunk_prep(const float* __restrict__ qb,
                                                 const float* __restrict__ kb,
                                                 const float* __restrict__ lfb,
                                                 const float* __restrict__ csb,
                                                 __bf16* __restrict__ ck_hat,
                                                 __bf16* __restrict__ ck_q,
                                                 __bf16* __restrict__ ck_kbT,
                                                 __bf16* __restrict__ ck_M,
                                                 __bf16* __restrict__ ck_G,
                                                 float* __restrict__ ck_lam) {
    __shared__ __align__(16) __bf16 khL[32][72];
    __shared__ __align__(16) __bf16 kbL[32][72];
    __shared__ __align__(16) __bf16 qtL[32][72];
    __shared__ float Afp[32][33];
    __shared__ float scl[3][32];
    const int bx = blockIdx.x;
    const int bh = bx >> 6, ci = bx & 63;
    const int b = bh >> 4, h = bh & 15;
    const int l = threadIdx.x;
    const int l15 = l & 15, quad = l >> 4, t32 = l & 31;
    const size_t cid = (size_t)bh * NC + ci;

    const size_t mb = ((size_t)(b * NN + ci * CT) + t32) * HH + h;
    float c_t = csb[mb];
    float p = lfb[mb];
#pragma unroll
    for (int d = 1; d <= 16; d <<= 1) {
        float o = __shfl_up(p, d);
        p *= (t32 >= d) ? o : 1.f;
    }
    float pm1 = __shfl_up(p, 1);
    if (t32 == 0) pm1 = 1.f;
    const float lamT = __shfl(p, 31);
    if (l < 32) {
        scl[0][t32] = c_t * pm1;  // khat scale
        scl[1][t32] = 1.f / p;    // kbar scale
        scl[2][t32] = p;          // qtil scale
    }
    if (l == 0) ck_lam[cid] = lamT;
    __syncthreads();

    const size_t rb0 = ((size_t)(b * NN + ci * CT)) * DD + h * HD;
    __bf16* khG = ck_hat + cid * 2048;
    __bf16* qtG = ck_q + cid * 2048;
    __bf16* kTG = ck_kbT + cid * 2048;
#pragma unroll
    for (int rep = 0; rep < 8; rep++) {
        const int row = rep * 4 + quad;
        const int c4 = l15 * 4;
        float4 kv = *(const float4*)(kb + rb0 + (size_t)row * DD + c4);
        float4 qv = *(const float4*)(qb + rb0 + (size_t)row * DD + c4);
        const float sh = scl[0][row], sbr = scl[1][row], sq = scl[2][row];
        bf16x4 khv, kbv, qtv;
        khv[0] = (__bf16)(kv.x * sh); khv[1] = (__bf16)(kv.y * sh);
        khv[2] = (__bf16)(kv.z * sh); khv[3] = (__bf16)(kv.w * sh);
        kbv[0] = (__bf16)(kv.x * sbr); kbv[1] = (__bf16)(kv.y * sbr);
        kbv[2] = (__bf16)(kv.z * sbr); kbv[3] = (__bf16)(kv.w * sbr);
        qtv[0] = (__bf16)(qv.x * sq); qtv[1] = (__bf16)(qv.y * sq);
        qtv[2] = (__bf16)(qv.z * sq); qtv[3] = (__bf16)(qv.w * sq);
        *(bf16x4*)&khL[row][c4] = khv;
        *(bf16x4*)&kbL[row][c4] = kbv;
        *(bf16x4*)&qtL[row][c4] = qtv;
        *(bf16x4*)(khG + row * 64 + c4) = khv;
        *(bf16x4*)(qtG + row * 64 + c4) = qtv;
#pragma unroll
        for (int j = 0; j < 4; j++) kTG[(c4 + j) * 32 + row] = kbv[j];
    }
    __syncthreads();

    __bf16* GG = ck_G + cid * 1024;
#pragma unroll
    for (int mi = 0; mi < 2; mi++)
#pragma unroll
        for (int ni = 0; ni < 2; ni++) {
            f32x4 aA = (f32x4){0.f, 0.f, 0.f, 0.f};
            f32x4 aG = (f32x4){0.f, 0.f, 0.f, 0.f};
#pragma unroll
            for (int k2 = 0; k2 < 2; k2++) {
                bf16x8 bfr = *(const bf16x8*)&kbL[ni * 16 + l15][k2 * 32 + quad * 8];
                bf16x8 afr = *(const bf16x8*)&khL[mi * 16 + l15][k2 * 32 + quad * 8];
                bf16x8 qfr = *(const bf16x8*)&qtL[mi * 16 + l15][k2 * 32 + quad * 8];
                aA = MFMA16(afr, bfr, aA);
                aG = MFMA16(qfr, bfr, aG);
            }
#pragma unroll
            for (int r = 0; r < 4; r++) {
                const int row = mi * 16 + quad * 4 + r, col = ni * 16 + l15;
                Afp[row][col] = (col < row) ? aA[r] : 0.f;
                GG[row * 32 + col] = (__bf16)((col <= row) ? aG[r] : 0.f);
            }
        }
    __syncthreads();

    __bf16* MG = ck_M + cid * 1024;
    if (l < 32) {
        float m[32];
#pragma unroll
        for (int t = 0; t < 32; t++) {
            float r = (l == t) ? 1.f : 0.f;
#pragma unroll
            for (int s = 0; s < t; s++) r += Afp[t][s] * m[s];
            m[t] = r;
            MG[t * 32 + l] = (__bf16)r;
        }
    }
}

// ---------------------------------------------------------------------------
// Chunked delta-rule, phase 2. (unchanged — verified round 4)
// ---------------------------------------------------------------------------
struct FragSet {
    bf16x8 ka[2][2], qa[2][2], ma[2], ga[2], kba[4];
    f32x4 vv[2];
    float lam;
};

__global__ __launch_bounds__(64) void chunk_scan(const __bf16* __restrict__ ck_hat,
                                                 const __bf16* __restrict__ ck_q,
                                                 const __bf16* __restrict__ ck_kbT,
                                                 const __bf16* __restrict__ ck_M,
                                                 const __bf16* __restrict__ ck_G,
                                                 const float* __restrict__ ck_lam,
                                                 const float* __restrict__ vb,
                                                 __bf16* __restrict__ obh) {
    __shared__ __align__(16) __bf16 Sbt[16][72];
    __shared__ __align__(16) __bf16 Vbt[16][40];
    __shared__ __align__(16) __bf16 Ubt[16][40];
    const int bx = blockIdx.x;
    const int bh = bx >> 2, vs = bx & 3;
    const int b = bh >> 4, h = bh & 15;
    const int l = threadIdx.x, l15 = l & 15, quad = l >> 4;
    const size_t cid0 = (size_t)bh * NC;
    const size_t vcol = (size_t)h * HD + vs * 16 + l15;
    const size_t rowb = (size_t)b * NN;

    f32x4 S[4];
#pragma unroll
    for (int dt = 0; dt < 4; dt++) S[dt] = (f32x4){0.f, 0.f, 0.f, 0.f};

    auto load = [&](FragSet& f, int ci) {
        const __bf16* khp = ck_hat + (cid0 + ci) * 2048;
        const __bf16* qp = ck_q + (cid0 + ci) * 2048;
        const __bf16* kTp = ck_kbT + (cid0 + ci) * 2048;
        const __bf16* Mp = ck_M + (cid0 + ci) * 1024;
        const __bf16* Gp = ck_G + (cid0 + ci) * 1024;
#pragma unroll
        for (int mi = 0; mi < 2; mi++) {
#pragma unroll
            for (int k2 = 0; k2 < 2; k2++) {
                f.ka[mi][k2] = *(const bf16x8*)(khp + (mi * 16 + l15) * 64 + k2 * 32 + quad * 8);
                f.qa[mi][k2] = *(const bf16x8*)(qp + (mi * 16 + l15) * 64 + k2 * 32 + quad * 8);
            }
            f.ma[mi] = *(const bf16x8*)(Mp + (mi * 16 + l15) * 32 + quad * 8);
            f.ga[mi] = *(const bf16x8*)(Gp + (mi * 16 + l15) * 32 + quad * 8);
        }
#pragma unroll
        for (int dt = 0; dt < 4; dt++)
            f.kba[dt] = *(const bf16x8*)(kTp + (dt * 16 + l15) * 32 + quad * 8);
#pragma unroll
        for (int mi = 0; mi < 2; mi++)
#pragma unroll
            for (int r = 0; r < 4; r++)
                f.vv[mi][r] = vb[(rowb + ci * CT + mi * 16 + quad * 4 + r) * DD + vcol];
        f.lam = ck_lam[cid0 + ci];
    };

    auto compute = [&](const FragSet& f, int ci) {
        const f32x4 z = (f32x4){0.f, 0.f, 0.f, 0.f};
#pragma unroll
        for (int dt = 0; dt < 4; dt++) {
            bf16x4 t;
#pragma unroll
            for (int r = 0; r < 4; r++) t[r] = (__bf16)S[dt][r];
            *(bf16x4*)&Sbt[l15][dt * 16 + quad * 4] = t;
        }
        bf16x8 sb0 = *(const bf16x8*)&Sbt[l15][quad * 8];
        bf16x8 sb1 = *(const bf16x8*)&Sbt[l15][32 + quad * 8];
        f32x4 p0 = MFMA16(f.ka[0][0], sb0, z); p0 = MFMA16(f.ka[0][1], sb1, p0);
        f32x4 p1 = MFMA16(f.ka[1][0], sb0, z); p1 = MFMA16(f.ka[1][1], sb1, p1);
        p0 += f.vv[0]; p1 += f.vv[1];
        bf16x4 t0, t1;
#pragma unroll
        for (int r = 0; r < 4; r++) { t0[r] = (__bf16)p0[r]; t1[r] = (__bf16)p1[r]; }
        *(bf16x4*)&Vbt[l15][quad * 4] = t0;
        *(bf16x4*)&Vbt[l15][16 + quad * 4] = t1;
        bf16x8 vfr = *(const bf16x8*)&Vbt[l15][quad * 8];
        f32x4 u0 = MFMA16(f.ma[0], vfr, z);
        f32x4 u1 = MFMA16(f.ma[1], vfr, z);
#pragma unroll
        for (int r = 0; r < 4; r++) { t0[r] = (__bf16)u0[r]; t1[r] = (__bf16)u1[r]; }
        *(bf16x4*)&Ubt[l15][quad * 4] = t0;
        *(bf16x4*)&Ubt[l15][16 + quad * 4] = t1;
        bf16x8 ufr = *(const bf16x8*)&Ubt[l15][quad * 8];
        f32x4 o0 = MFMA16(f.qa[0][0], sb0, z); o0 = MFMA16(f.qa[0][1], sb1, o0);
        o0 = MFMA16(f.ga[0], ufr, o0);
        f32x4 o1 = MFMA16(f.qa[1][0], sb0, z); o1 = MFMA16(f.qa[1][1], sb1, o1);
        o1 = MFMA16(f.ga[1], ufr, o1);
#pragma unroll
        for (int r = 0; r < 4; r++) {
            obh[(rowb + ci * CT + quad * 4 + r) * DD + vcol] = (__bf16)o0[r];
            obh[(rowb + ci * CT + 16 + quad * 4 + r) * DD + vcol] = (__bf16)o1[r];
        }
#pragma unroll
        for (int dt = 0; dt < 4; dt++) {
            S[dt] = MFMA16(f.kba[dt], ufr, S[dt]);
#pragma unroll
            for (int r = 0; r < 4; r++) S[dt][r] *= f.lam;
        }
    };

    FragSet fA, fB;
    load(fA, 0);
    for (int ci = 0; ci < NC; ci += 2) {
        load(fB, ci + 1);
        __builtin_amdgcn_sched_barrier(0);
        compute(fA, ci);
        load(fA, (ci + 2 < NC) ? ci + 2 : NC - 1);
        __builtin_amdgcn_sched_barrier(0);
        compute(fB, ci + 1);
    }
}

// ---------------------------------------------------------------------------
// lnob = bf16( LayerNorm(o * sigmoid(gatep)) * norm_w ). (unchanged)
// ---------------------------------------------------------------------------
__global__ __launch_bounds__(256) void gate_ln_kernel(const __bf16* __restrict__ obh,
                                                      const float* __restrict__ gatep,
                                                      const float* __restrict__ nw,
                                                      __bf16* __restrict__ lnob) {
    const int r = blockIdx.x, tid = threadIdx.x;
    const int wav = tid >> 6, lane = tid & 63;
    __shared__ float red[8];
    const size_t rb = (size_t)r * DD;

    float vals[4];
    float s = 0.f;
#pragma unroll
    for (int p = 0; p < 4; p++) {
        const int j = tid + 256 * p;
        float xg = (float)obh[rb + j] * sigmoidf_(gatep[rb + j]);
        vals[p] = xg;
        s += xg;
    }
#pragma unroll
    for (int m = 1; m <= 32; m <<= 1) s += __shfl_xor(s, m);
    if (lane == 0) red[wav] = s;
    __syncthreads();
    const float mu = (red[0] + red[1] + red[2] + red[3]) * (1.f / 1024.f);

    float s2 = 0.f;
#pragma unroll
    for (int p = 0; p < 4; p++) { float d = vals[p] - mu; s2 += d * d; }
#pragma unroll
    for (int m = 1; m <= 32; m <<= 1) s2 += __shfl_xor(s2, m);
    if (lane == 0) red[4 + wav] = s2;
    __syncthreads();
    const float var = (red[4] + red[5] + red[6] + red[7]) * (1.f / 1024.f);
    const float rs = rsqrtf(var + 1e-5f);

#pragma unroll
    for (int p = 0; p < 4; p++) {
        const int j = tid + 256 * p;
        lnob[rb + j] = (__bf16)((vals[p] - mu) * rs * nw[j]);
    }
}

// ---------------------------------------------------------------------------
extern "C" void kernel_launch(void* const* d_in, const int* in_sizes, int n_in,
                              void* d_out, int out_size, void* d_ws, size_t ws_size,
                              hipStream_t stream) {
    const float* x   = (const float*)d_in[0];
    const float* Wq  = (const float*)d_in[1];
    const float* Wk  = (const float*)d_in[2];
    const float* Wv  = (const float*)d_in[3];
    const float* Wgm = (const float*)d_in[4];  // Wgamma
    const float* Wf  = (const float*)d_in[5];
    const float* Wg1 = (const float*)d_in[6];
    const float* Wg2 = (const float*)d_in[7];
    const float* Wo  = (const float*)d_in[8];
    const float* nw  = (const float*)d_in[9];
    float* out = (float*)d_out;

    float* w = (float*)d_ws;
    float* qb    = w;                     // 4096x1024 f32 (later reused as lnob bf16)
    float* kb    = qb + 4194304;
    float* vb    = kb + 4194304;
    float* gatep = vb + 4194304;
    __bf16* g1b  = (__bf16*)(gatep + 4194304);  // 4096x64 bf16 (131072 f32 slot)
    float* lfb   = gatep + 4194304 + 131072;    // 4096x16 (lambda)
    float* csb   = lfb + 65536;                 // 4096x16 (gamma*lambda^2)
    __bf16* obh  = (__bf16*)(csb + 65536);      // 4096x1024 bf16 scan output
    float* cw    = csb + 65536 + 2097152;       // chunk workspace
    __bf16* ck_hat = (__bf16*)cw;               // [2048][32][64] bf16
    __bf16* ck_q   = (__bf16*)(cw + 2097152);   // [2048][32][64]
    __bf16* ck_kbT = (__bf16*)(cw + 4194304);   // [2048][64][32]
    __bf16* ck_M   = (__bf16*)(cw + 6291456);   // [2048][32][32]
    __bf16* ck_G   = (__bf16*)(cw + 7340032);   // [2048][32][32]
    float*  ck_lam = cw + 8388608;              // [2048]
    float* nw2   = cw + 8390656;
    __bf16* xb   = (__bf16*)nw2;                // 4096x1024 bf16
    __bf16* WqT  = (__bf16*)(nw2 + 2097152);    // 1024x1024 bf16 (transposed)
    __bf16* WkT  = (__bf16*)(nw2 + 2621440);
    __bf16* WvT  = (__bf16*)(nw2 + 3145728);
    __bf16* WoT  = (__bf16*)(nw2 + 3670016);
    __bf16* Wg2T = (__bf16*)(nw2 + 4194304);    // 1024x64 bf16
    __bf16* W96T = (__bf16*)(nw2 + 4227072);    // 128x1024 bf16 (padded)
    float* c96   = nw2 + 4292608;               // 4096x128 f32
    __bf16* lnob = (__bf16*)qb;                 // reuse qb

    dim3 blk(256);
    xcvt<<<2048, blk, 0, stream>>>(x, xb);
    wtrans<<<dim3(16, 16, 4), blk, 0, stream>>>(Wq, Wk, Wv, Wo, WqT, WkT, WvT, WoT,
                                                DD, DD);
    wtrans<<<dim3(16, 1, 1), blk, 0, stream>>>(Wg2, Wg2, Wg2, Wg2, Wg2T, Wg2T, Wg2T,
                                               Wg2T, HD, DD);
    wtrans96<<<128, blk, 0, stream>>>(Wgm, Wf, Wg1, W96T);
    // fused q,k,v + 96-col proj: 25 x-blocks = 3x8 col-tiles + 1 (mat 3, N=128)
    gemm_bt<<<dim3(25, 32), blk, 0, stream>>>(xb, WqT, WkT, WvT, W96T,
                                              qb, kb, vb, c96, RR, DD, DD);
    prep_kernel<<<RR * HH / 4, blk, 0, stream>>>(qb, kb, vb, c96, lfb, csb, g1b);
    gemm_bt<<<dim3(8, 32), blk, 0, stream>>>(g1b, Wg2T, Wg2T, Wg2T, Wg2T,
                                             gatep, gatep, gatep, gatep, RR, DD, HD);
    chunk_prep<<<32 * NC, 64, 0, stream>>>(qb, kb, lfb, csb,
                                           ck_hat, ck_q, ck_kbT, ck_M, ck_G, ck_lam);
    chunk_scan<<<128, 64, 0, stream>>>(ck_hat, ck_q, ck_kbT, ck_M, ck_G, ck_lam, vb, obh);
    gate_ln_kernel<<<RR, blk, 0, stream>>>(obh, gatep, nw, lnob);
    gemm_bt<<<dim3(8, 32), blk, 0, stream>>>(lnob, WoT, WoT, WoT, WoT,
                                             out, out, out, out, RR, DD, DD);
}

// Round 7
// 281.879 us; speedup vs baseline: 4.9037x; 1.0380x over previous
//
#include <hip/hip_runtime.h>

#define BB 2
#define NN 2048
#define DD 1024
#define HH 16
#define HD 64
#define RR (BB * NN)  // 4096 rows
#define CT 32         // chunk length (steps)
#define NC (NN / CT)  // 64 chunks per (b,h)

typedef __bf16 bf16x8 __attribute__((ext_vector_type(8)));
typedef __bf16 bf16x4 __attribute__((ext_vector_type(4)));
typedef float f32x4 __attribute__((ext_vector_type(4)));
typedef float f32x2 __attribute__((ext_vector_type(2)));

__device__ __forceinline__ float sigmoidf_(float x) { return 1.f / (1.f + __expf(-x)); }

#define MFMA16(a, b, c) __builtin_amdgcn_mfma_f32_16x16x32_bf16((a), (b), (c), 0, 0, 0)

// async global -> LDS DMA (gfx950). LDS dst is wave-uniform; lane i's data
// lands at dst + i*size. Global src is a normal per-lane address.
__device__ __forceinline__ void gl2lds16(const void* g, void* l) {
    __builtin_amdgcn_global_load_lds((const __attribute__((address_space(1))) void*)g,
                                     (__attribute__((address_space(3))) void*)l, 16, 0, 0);
}
__device__ __forceinline__ void gl2lds4(const void* g, void* l) {
    __builtin_amdgcn_global_load_lds((const __attribute__((address_space(1))) void*)g,
                                     (__attribute__((address_space(3))) void*)l, 4, 0, 0);
}

// ---------------------------------------------------------------------------
// x (f32) -> bf16, 8 elems/thread.
// ---------------------------------------------------------------------------
__global__ __launch_bounds__(256) void xcvt(const float* __restrict__ x,
                                            __bf16* __restrict__ xb) {
    const size_t i = ((size_t)blockIdx.x * 256 + threadIdx.x) * 8;
    float4 a = *(const float4*)(x + i);
    float4 b = *(const float4*)(x + i + 4);
    bf16x8 o;
    o[0] = (__bf16)a.x; o[1] = (__bf16)a.y; o[2] = (__bf16)a.z; o[3] = (__bf16)a.w;
    o[4] = (__bf16)b.x; o[5] = (__bf16)b.y; o[6] = (__bf16)b.z; o[7] = (__bf16)b.w;
    *(bf16x8*)(xb + i) = o;
}

// ---------------------------------------------------------------------------
// Weight transpose+convert: S (f32, [K][N]) -> D (bf16, [N][K]).
// 64x64 tiles via LDS. blockIdx.z selects among 4 matrices. (unchanged)
// ---------------------------------------------------------------------------
__global__ __launch_bounds__(256) void wtrans(const float* S0, const float* S1,
                                              const float* S2, const float* S3,
                                              __bf16* D0, __bf16* D1,
                                              __bf16* D2, __bf16* D3,
                                              int K, int N) {
    __shared__ float t[64][65];
    const int z = blockIdx.z;
    const float* S = (z == 0) ? S0 : ((z == 1) ? S1 : ((z == 2) ? S2 : S3));
    __bf16* D = (z == 0) ? D0 : ((z == 1) ? D1 : ((z == 2) ? D2 : D3));
    const int tid = threadIdx.x;
    const int ti = blockIdx.y * 64;  // k tile
    const int tj = blockIdx.x * 64;  // n tile
    const int r = tid >> 2, c0 = (tid & 3) * 16;
    const float* sp = S + (size_t)(ti + r) * N + tj + c0;
#pragma unroll
    for (int p = 0; p < 4; p++) {
        float4 v = *(const float4*)(sp + 4 * p);
        t[r][c0 + 4 * p + 0] = v.x; t[r][c0 + 4 * p + 1] = v.y;
        t[r][c0 + 4 * p + 2] = v.z; t[r][c0 + 4 * p + 3] = v.w;
    }
    __syncthreads();
    bf16x8 o0, o1;
#pragma unroll
    for (int j = 0; j < 8; j++) o0[j] = (__bf16)t[c0 + j][r];
#pragma unroll
    for (int j = 0; j < 8; j++) o1[j] = (__bf16)t[c0 + 8 + j][r];
    __bf16* dp = D + (size_t)(tj + r) * K + ti + c0;
    *(bf16x8*)dp = o0;
    *(bf16x8*)(dp + 8) = o1;
}

// ---------------------------------------------------------------------------
// W96T[c][k] (bf16, 128x1024, zero-padded rows 96..127) = [Wgamma|Wf|Wg1]^T.
// ---------------------------------------------------------------------------
__global__ __launch_bounds__(256) void wtrans96(const float* __restrict__ Wgm,
                                                const float* __restrict__ Wf,
                                                const float* __restrict__ Wg1,
                                                __bf16* __restrict__ W96T) {
    const int c = blockIdx.x;        // 0..127
    const int k0 = threadIdx.x * 4;  // 0..1020
    bf16x4 o;
    if (c < 96) {
        const float* src;
        int stride;
        if (c < 16)      { src = Wgm + c;        stride = 16; }
        else if (c < 32) { src = Wf + (c - 16);  stride = 16; }
        else             { src = Wg1 + (c - 32); stride = 64; }
#pragma unroll
        for (int j = 0; j < 4; j++) o[j] = (__bf16)src[(size_t)(k0 + j) * stride];
    } else {
        o[0] = o[1] = o[2] = o[3] = (__bf16)0.f;
    }
    *(bf16x4*)(W96T + (size_t)c * 1024 + k0) = o;
}

// ---------------------------------------------------------------------------
// bf16 GEMM, m97 structure: C[M,Nn](f32) = A[M,K](bf16) @ BT[Nn,K]^T.
// LINEAR LDS [128][32] bf16 staged by global_load_lds width=16 (4 instr/wave
// per K-step); no VGPR round-trip, no padding (DMA lands lane i at base+i*16
// == row-major [16][32]). Fragment reads / MFMA / C-write unchanged from the
// verified kernel (only LDS row stride 40->32).
// Block-selected B/C pairs: grid.x = 8*nmat (+1 for the 128-col mat 3).
// ---------------------------------------------------------------------------
__global__ __launch_bounds__(256) void gemm_bt(const __bf16* __restrict__ A,
                                               const __bf16* B0, const __bf16* B1,
                                               const __bf16* B2, const __bf16* B3,
                                               float* C0, float* C1, float* C2, float* C3,
                                               int M, int N, int K) {
    constexpr int BK = 32;
    __shared__ __align__(16) __bf16 As[128 * BK];
    __shared__ __align__(16) __bf16 Bs[128 * BK];
    const int mat = blockIdx.x >> 3;
    const __bf16* B = (mat == 0) ? B0 : ((mat == 1) ? B1 : ((mat == 2) ? B2 : B3));
    float* C = (mat == 0) ? C0 : ((mat == 1) ? C1 : ((mat == 2) ? C2 : C3));
    const int Nn = (mat == 3) ? 128 : N;
    const int tid = threadIdx.x;
    const int lane = tid & 63;
    const int wave = tid >> 6;
    const int wm = (wave >> 1) * 64, wn = (wave & 1) * 64;
    const int bm = blockIdx.y * 128, bn = (blockIdx.x & 7) * 128;
    const int l15 = lane & 15, quad = lane >> 4;

    // staging: lane -> (row = lane>>2, 16B at col (lane&3)*8); wave w covers
    // rows w*16..w*16+15 and +64 (2 instr per matrix).
    const int srow = lane >> 2, scol = (lane & 3) * 8;
    const __bf16* gA = A + (size_t)(bm + wave * 16 + srow) * K + scol;
    const __bf16* gB = B + (size_t)(bn + wave * 16 + srow) * K + scol;
    const size_t rstep = (size_t)64 * K;
    __bf16* lA0 = &As[(wave * 16) * BK];
    __bf16* lA1 = &As[(wave * 16 + 64) * BK];
    __bf16* lB0 = &Bs[(wave * 16) * BK];
    __bf16* lB1 = &Bs[(wave * 16 + 64) * BK];

    f32x4 acc[4][4];
#pragma unroll
    for (int i = 0; i < 4; i++)
#pragma unroll
        for (int j = 0; j < 4; j++) acc[i][j] = (f32x4){0.f, 0.f, 0.f, 0.f};

    for (int kb = 0; kb < K; kb += BK) {
        gl2lds16(gA + kb, lA0);
        gl2lds16(gA + kb + rstep, lA1);
        gl2lds16(gB + kb, lB0);
        gl2lds16(gB + kb + rstep, lB1);
        asm volatile("s_waitcnt vmcnt(0)" ::: "memory");
        __syncthreads();

        bf16x8 af[4], bfr[4];
#pragma unroll
        for (int i = 0; i < 4; i++)
            af[i] = *(const bf16x8*)&As[(wm + i * 16 + l15) * BK + quad * 8];
#pragma unroll
        for (int j = 0; j < 4; j++)
            bfr[j] = *(const bf16x8*)&Bs[(wn + j * 16 + l15) * BK + quad * 8];
#pragma unroll
        for (int i = 0; i < 4; i++)
#pragma unroll
            for (int j = 0; j < 4; j++)
                acc[i][j] = MFMA16(af[i], bfr[j], acc[i][j]);
        __syncthreads();  // frag reads done (consumed by MFMA) before next DMA
    }

#pragma unroll
    for (int i = 0; i < 4; i++) {
#pragma unroll
        for (int r = 0; r < 4; r++) {
            const int row = bm + wm + i * 16 + quad * 4 + r;
            float* cp = C + (size_t)row * Nn + bn + wn + l15;
#pragma unroll
            for (int j = 0; j < 4; j++) cp[j * 16] = acc[i][j][r];
        }
    }
}

// ---------------------------------------------------------------------------
// Post-projection elementwise. One wave per (row, head). (unchanged)
// ---------------------------------------------------------------------------
__global__ __launch_bounds__(256) void prep_kernel(float* qb, float* kb, float* vb,
                                                   const float* __restrict__ c96,
                                                   float* lfb, float* csb,
                                                   __bf16* __restrict__ g1b) {
    const int tid = threadIdx.x;
    const int wav = tid >> 6, lane = tid & 63;
    const int gid = blockIdx.x * 4 + wav;  // (r,h)
    const int r = gid >> 4, h = gid & 15;
    const size_t idx = (size_t)r * DD + (size_t)h * HD + lane;

    float xq = qb[idx], xk = kb[idx], xv = vb[idx];
    float q = xq * sigmoidf_(xq);
    float v = xv * sigmoidf_(xv);
    float kk = xk * sigmoidf_(xk);
    float ss = kk * kk;
#pragma unroll
    for (int m = 1; m <= 32; m <<= 1) ss += __shfl_xor(ss, m);
    float norm = fmaxf(sqrtf(ss), 1e-12f);
    float kn = kk / norm;

    float f = c96[(size_t)r * 128 + 16 + h];
    float sig = sigmoidf_(f);                                  // lambda
    float gm = -sigmoidf_(c96[(size_t)r * 128 + h]);           // gamma

    qb[idx] = q;
    vb[idx] = v;
    kb[idx] = kn;
    if (lane == 0) {
        lfb[(size_t)r * HH + h] = sig;
        csb[(size_t)r * HH + h] = gm * sig * sig;
    }
    if (h == 0) g1b[(size_t)r * 64 + lane] = (__bf16)c96[(size_t)r * 128 + 32 + lane];
}

// ---------------------------------------------------------------------------
// Chunked delta-rule, phase 1. (unchanged — verified round 4)
// ---------------------------------------------------------------------------
__global__ __launch_bounds__(64) void chunk_prep(const float* __restrict__ qb,
                                                 const float* __restrict__ kb,
                                                 const float* __restrict__ lfb,
                                                 const float* __restrict__ csb,
                                                 __bf16* __restrict__ ck_hat,
                                                 __bf16* __restrict__ ck_q,
                                                 __bf16* __restrict__ ck_kbT,
                                                 __bf16* __restrict__ ck_M,
                                                 __bf16* __restrict__ ck_G,
                                                 float* __restrict__ ck_lam) {
    __shared__ __align__(16) __bf16 khL[32][72];
    __shared__ __align__(16) __bf16 kbL[32][72];
    __shared__ __align__(16) __bf16 qtL[32][72];
    __shared__ float Afp[32][33];
    __shared__ float scl[3][32];
    const int bx = blockIdx.x;
    const int bh = bx >> 6, ci = bx & 63;
    const int b = bh >> 4, h = bh & 15;
    const int l = threadIdx.x;
    const int l15 = l & 15, quad = l >> 4, t32 = l & 31;
    const size_t cid = (size_t)bh * NC + ci;

    const size_t mb = ((size_t)(b * NN + ci * CT) + t32) * HH + h;
    float c_t = csb[mb];
    float p = lfb[mb];
#pragma unroll
    for (int d = 1; d <= 16; d <<= 1) {
        float o = __shfl_up(p, d);
        p *= (t32 >= d) ? o : 1.f;
    }
    float pm1 = __shfl_up(p, 1);
    if (t32 == 0) pm1 = 1.f;
    const float lamT = __shfl(p, 31);
    if (l < 32) {
        scl[0][t32] = c_t * pm1;  // khat scale
        scl[1][t32] = 1.f / p;    // kbar scale
        scl[2][t32] = p;          // qtil scale
    }
    if (l == 0) ck_lam[cid] = lamT;
    __syncthreads();

    const size_t rb0 = ((size_t)(b * NN + ci * CT)) * DD + h * HD;
    __bf16* khG = ck_hat + cid * 2048;
    __bf16* qtG = ck_q + cid * 2048;
    __bf16* kTG = ck_kbT + cid * 2048;
#pragma unroll
    for (int rep = 0; rep < 8; rep++) {
        const int row = rep * 4 + quad;
        const int c4 = l15 * 4;
        float4 kv = *(const float4*)(kb + rb0 + (size_t)row * DD + c4);
        float4 qv = *(const float4*)(qb + rb0 + (size_t)row * DD + c4);
        const float sh = scl[0][row], sbr = scl[1][row], sq = scl[2][row];
        bf16x4 khv, kbv, qtv;
        khv[0] = (__bf16)(kv.x * sh); khv[1] = (__bf16)(kv.y * sh);
        khv[2] = (__bf16)(kv.z * sh); khv[3] = (__bf16)(kv.w * sh);
        kbv[0] = (__bf16)(kv.x * sbr); kbv[1] = (__bf16)(kv.y * sbr);
        kbv[2] = (__bf16)(kv.z * sbr); kbv[3] = (__bf16)(kv.w * sbr);
        qtv[0] = (__bf16)(qv.x * sq); qtv[1] = (__bf16)(qv.y * sq);
        qtv[2] = (__bf16)(qv.z * sq); qtv[3] = (__bf16)(qv.w * sq);
        *(bf16x4*)&khL[row][c4] = khv;
        *(bf16x4*)&kbL[row][c4] = kbv;
        *(bf16x4*)&qtL[row][c4] = qtv;
        *(bf16x4*)(khG + row * 64 + c4) = khv;
        *(bf16x4*)(qtG + row * 64 + c4) = qtv;
#pragma unroll
        for (int j = 0; j < 4; j++) kTG[(c4 + j) * 32 + row] = kbv[j];
    }
    __syncthreads();

    __bf16* GG = ck_G + cid * 1024;
#pragma unroll
    for (int mi = 0; mi < 2; mi++)
#pragma unroll
        for (int ni = 0; ni < 2; ni++) {
            f32x4 aA = (f32x4){0.f, 0.f, 0.f, 0.f};
            f32x4 aG = (f32x4){0.f, 0.f, 0.f, 0.f};
#pragma unroll
            for (int k2 = 0; k2 < 2; k2++) {
                bf16x8 bfr = *(const bf16x8*)&kbL[ni * 16 + l15][k2 * 32 + quad * 8];
                bf16x8 afr = *(const bf16x8*)&khL[mi * 16 + l15][k2 * 32 + quad * 8];
                bf16x8 qfr = *(const bf16x8*)&qtL[mi * 16 + l15][k2 * 32 + quad * 8];
                aA = MFMA16(afr, bfr, aA);
                aG = MFMA16(qfr, bfr, aG);
            }
#pragma unroll
            for (int r = 0; r < 4; r++) {
                const int row = mi * 16 + quad * 4 + r, col = ni * 16 + l15;
                Afp[row][col] = (col < row) ? aA[r] : 0.f;
                GG[row * 32 + col] = (__bf16)((col <= row) ? aG[r] : 0.f);
            }
        }
    __syncthreads();

    __bf16* MG = ck_M + cid * 1024;
    if (l < 32) {
        float m[32];
#pragma unroll
        for (int t = 0; t < 32; t++) {
            float r = (l == t) ? 1.f : 0.f;
#pragma unroll
            for (int s = 0; s < t; s++) r += Afp[t][s] * m[s];
            m[t] = r;
            MG[t * 32 + l] = (__bf16)r;
        }
    }
}

// ---------------------------------------------------------------------------
// Chunked delta-rule, phase 2. (unchanged — verified round 4)
// ---------------------------------------------------------------------------
struct FragSet {
    bf16x8 ka[2][2], qa[2][2], ma[2], ga[2], kba[4];
    f32x4 vv[2];
    float lam;
};

__global__ __launch_bounds__(64) void chunk_scan(const __bf16* __restrict__ ck_hat,
                                                 const __bf16* __restrict__ ck_q,
                                                 const __bf16* __restrict__ ck_kbT,
                                                 const __bf16* __restrict__ ck_M,
                                                 const __bf16* __restrict__ ck_G,
                                                 const float* __restrict__ ck_lam,
                                                 const float* __restrict__ vb,
                                                 __bf16* __restrict__ obh) {
    __shared__ __align__(16) __bf16 Sbt[16][72];
    __shared__ __align__(16) __bf16 Vbt[16][40];
    __shared__ __align__(16) __bf16 Ubt[16][40];
    const int bx = blockIdx.x;
    const int bh = bx >> 2, vs = bx & 3;
    const int b = bh >> 4, h = bh & 15;
    const int l = threadIdx.x, l15 = l & 15, quad = l >> 4;
    const size_t cid0 = (size_t)bh * NC;
    const size_t vcol = (size_t)h * HD + vs * 16 + l15;
    const size_t rowb = (size_t)b * NN;

    f32x4 S[4];
#pragma unroll
    for (int dt = 0; dt < 4; dt++) S[dt] = (f32x4){0.f, 0.f, 0.f, 0.f};

    auto load = [&](FragSet& f, int ci) {
        const __bf16* khp = ck_hat + (cid0 + ci) * 2048;
        const __bf16* qp = ck_q + (cid0 + ci) * 2048;
        const __bf16* kTp = ck_kbT + (cid0 + ci) * 2048;
        const __bf16* Mp = ck_M + (cid0 + ci) * 1024;
        const __bf16* Gp = ck_G + (cid0 + ci) * 1024;
#pragma unroll
        for (int mi = 0; mi < 2; mi++) {
#pragma unroll
            for (int k2 = 0; k2 < 2; k2++) {
                f.ka[mi][k2] = *(const bf16x8*)(khp + (mi * 16 + l15) * 64 + k2 * 32 + quad * 8);
                f.qa[mi][k2] = *(const bf16x8*)(qp + (mi * 16 + l15) * 64 + k2 * 32 + quad * 8);
            }
            f.ma[mi] = *(const bf16x8*)(Mp + (mi * 16 + l15) * 32 + quad * 8);
            f.ga[mi] = *(const bf16x8*)(Gp + (mi * 16 + l15) * 32 + quad * 8);
        }
#pragma unroll
        for (int dt = 0; dt < 4; dt++)
            f.kba[dt] = *(const bf16x8*)(kTp + (dt * 16 + l15) * 32 + quad * 8);
#pragma unroll
        for (int mi = 0; mi < 2; mi++)
#pragma unroll
            for (int r = 0; r < 4; r++)
                f.vv[mi][r] = vb[(rowb + ci * CT + mi * 16 + quad * 4 + r) * DD + vcol];
        f.lam = ck_lam[cid0 + ci];
    };

    auto compute = [&](const FragSet& f, int ci) {
        const f32x4 z = (f32x4){0.f, 0.f, 0.f, 0.f};
#pragma unroll
        for (int dt = 0; dt < 4; dt++) {
            bf16x4 t;
#pragma unroll
            for (int r = 0; r < 4; r++) t[r] = (__bf16)S[dt][r];
            *(bf16x4*)&Sbt[l15][dt * 16 + quad * 4] = t;
        }
        bf16x8 sb0 = *(const bf16x8*)&Sbt[l15][quad * 8];
        bf16x8 sb1 = *(const bf16x8*)&Sbt[l15][32 + quad * 8];
        f32x4 p0 = MFMA16(f.ka[0][0], sb0, z); p0 = MFMA16(f.ka[0][1], sb1, p0);
        f32x4 p1 = MFMA16(f.ka[1][0], sb0, z); p1 = MFMA16(f.ka[1][1], sb1, p1);
        p0 += f.vv[0]; p1 += f.vv[1];
        bf16x4 t0, t1;
#pragma unroll
        for (int r = 0; r < 4; r++) { t0[r] = (__bf16)p0[r]; t1[r] = (__bf16)p1[r]; }
        *(bf16x4*)&Vbt[l15][quad * 4] = t0;
        *(bf16x4*)&Vbt[l15][16 + quad * 4] = t1;
        bf16x8 vfr = *(const bf16x8*)&Vbt[l15][quad * 8];
        f32x4 u0 = MFMA16(f.ma[0], vfr, z);
        f32x4 u1 = MFMA16(f.ma[1], vfr, z);
#pragma unroll
        for (int r = 0; r < 4; r++) { t0[r] = (__bf16)u0[r]; t1[r] = (__bf16)u1[r]; }
        *(bf16x4*)&Ubt[l15][quad * 4] = t0;
        *(bf16x4*)&Ubt[l15][16 + quad * 4] = t1;
        bf16x8 ufr = *(const bf16x8*)&Ubt[l15][quad * 8];
        f32x4 o0 = MFMA16(f.qa[0][0], sb0, z); o0 = MFMA16(f.qa[0][1], sb1, o0);
        o0 = MFMA16(f.ga[0], ufr, o0);
        f32x4 o1 = MFMA16(f.qa[1][0], sb0, z); o1 = MFMA16(f.qa[1][1], sb1, o1);
        o1 = MFMA16(f.ga[1], ufr, o1);
#pragma unroll
        for (int r = 0; r < 4; r++) {
            obh[(rowb + ci * CT + quad * 4 + r) * DD + vcol] = (__bf16)o0[r];
            obh[(rowb + ci * CT + 16 + quad * 4 + r) * DD + vcol] = (__bf16)o1[r];
        }
#pragma unroll
        for (int dt = 0; dt < 4; dt++) {
            S[dt] = MFMA16(f.kba[dt], ufr, S[dt]);
#pragma unroll
            for (int r = 0; r < 4; r++) S[dt][r] *= f.lam;
        }
    };

    FragSet fA, fB;
    load(fA, 0);
    for (int ci = 0; ci < NC; ci += 2) {
        load(fB, ci + 1);
        __builtin_amdgcn_sched_barrier(0);
        compute(fA, ci);
        load(fA, (ci + 2 < NC) ? ci + 2 : NC - 1);
        __builtin_amdgcn_sched_barrier(0);
        compute(fB, ci + 1);
    }
}

// ---------------------------------------------------------------------------
// lnob = bf16( LayerNorm(o * sigmoid(gatep)) * norm_w ). (unchanged)
// ---------------------------------------------------------------------------
__global__ __launch_bounds__(256) void gate_ln_kernel(const __bf16* __restrict__ obh,
                                                      const float* __restrict__ gatep,
                                                      const float* __restrict__ nw,
                                                      __bf16* __restrict__ lnob) {
    const int r = blockIdx.x, tid = threadIdx.x;
    const int wav = tid >> 6, lane = tid & 63;
    __shared__ float red[8];
    const size_t rb = (size_t)r * DD;

    float vals[4];
    float s = 0.f;
#pragma unroll
    for (int p = 0; p < 4; p++) {
        const int j = tid + 256 * p;
        float xg = (float)obh[rb + j] * sigmoidf_(gatep[rb + j]);
        vals[p] = xg;
        s += xg;
    }
#pragma unroll
    for (int m = 1; m <= 32; m <<= 1) s += __shfl_xor(s, m);
    if (lane == 0) red[wav] = s;
    __syncthreads();
    const float mu = (red[0] + red[1] + red[2] + red[3]) * (1.f / 1024.f);

    float s2 = 0.f;
#pragma unroll
    for (int p = 0; p < 4; p++) { float d = vals[p] - mu; s2 += d * d; }
#pragma unroll
    for (int m = 1; m <= 32; m <<= 1) s2 += __shfl_xor(s2, m);
    if (lane == 0) red[4 + wav] = s2;
    __syncthreads();
    const float var = (red[4] + red[5] + red[6] + red[7]) * (1.f / 1024.f);
    const float rs = rsqrtf(var + 1e-5f);

#pragma unroll
    for (int p = 0; p < 4; p++) {
        const int j = tid + 256 * p;
        lnob[rb + j] = (__bf16)((vals[p] - mu) * rs * nw[j]);
    }
}

// ---------------------------------------------------------------------------
extern "C" void kernel_launch(void* const* d_in, const int* in_sizes, int n_in,
                              void* d_out, int out_size, void* d_ws, size_t ws_size,
                              hipStream_t stream) {
    const float* x   = (const float*)d_in[0];
    const float* Wq  = (const float*)d_in[1];
    const float* Wk  = (const float*)d_in[2];
    const float* Wv  = (const float*)d_in[3];
    const float* Wgm = (const float*)d_in[4];  // Wgamma
    const float* Wf  = (const float*)d_in[5];
    const float* Wg1 = (const float*)d_in[6];
    const float* Wg2 = (const float*)d_in[7];
    const float* Wo  = (const float*)d_in[8];
    const float* nw  = (const float*)d_in[9];
    float* out = (float*)d_out;

    float* w = (float*)d_ws;
    float* qb    = w;                     // 4096x1024 f32 (later reused as lnob bf16)
    float* kb    = qb + 4194304;
    float* vb    = kb + 4194304;
    float* gatep = vb + 4194304;
    __bf16* g1b  = (__bf16*)(gatep + 4194304);  // 4096x64 bf16 (131072 f32 slot)
    float* lfb   = gatep + 4194304 + 131072;    // 4096x16 (lambda)
    float* csb   = lfb + 65536;                 // 4096x16 (gamma*lambda^2)
    __bf16* obh  = (__bf16*)(csb + 65536);      // 4096x1024 bf16 scan output
    float* cw    = csb + 65536 + 2097152;       // chunk workspace
    __bf16* ck_hat = (__bf16*)cw;               // [2048][32][64] bf16
    __bf16* ck_q   = (__bf16*)(cw + 2097152);   // [2048][32][64]
    __bf16* ck_kbT = (__bf16*)(cw + 4194304);   // [2048][64][32]
    __bf16* ck_M   = (__bf16*)(cw + 6291456);   // [2048][32][32]
    __bf16* ck_G   = (__bf16*)(cw + 7340032);   // [2048][32][32]
    float*  ck_lam = cw + 8388608;              // [2048]
    float* nw2   = cw + 8390656;
    __bf16* xb   = (__bf16*)nw2;                // 4096x1024 bf16
    __bf16* WqT  = (__bf16*)(nw2 + 2097152);    // 1024x1024 bf16 (transposed)
    __bf16* WkT  = (__bf16*)(nw2 + 2621440);
    __bf16* WvT  = (__bf16*)(nw2 + 3145728);
    __bf16* WoT  = (__bf16*)(nw2 + 3670016);
    __bf16* Wg2T = (__bf16*)(nw2 + 4194304);    // 1024x64 bf16
    __bf16* W96T = (__bf16*)(nw2 + 4227072);    // 128x1024 bf16 (padded)
    float* c96   = nw2 + 4292608;               // 4096x128 f32
    __bf16* lnob = (__bf16*)qb;                 // reuse qb

    dim3 blk(256);
    xcvt<<<2048, blk, 0, stream>>>(x, xb);
    wtrans<<<dim3(16, 16, 4), blk, 0, stream>>>(Wq, Wk, Wv, Wo, WqT, WkT, WvT, WoT,
                                                DD, DD);
    wtrans<<<dim3(16, 1, 1), blk, 0, stream>>>(Wg2, Wg2, Wg2, Wg2, Wg2T, Wg2T, Wg2T,
                                               Wg2T, HD, DD);
    wtrans96<<<128, blk, 0, stream>>>(Wgm, Wf, Wg1, W96T);
    // fused q,k,v + 96-col proj: 25 x-blocks = 3x8 col-tiles + 1 (mat 3, N=128)
    gemm_bt<<<dim3(25, 32), blk, 0, stream>>>(xb, WqT, WkT, WvT, W96T,
                                              qb, kb, vb, c96, RR, DD, DD);
    prep_kernel<<<RR * HH / 4, blk, 0, stream>>>(qb, kb, vb, c96, lfb, csb, g1b);
    gemm_bt<<<dim3(8, 32), blk, 0, stream>>>(g1b, Wg2T, Wg2T, Wg2T, Wg2T,
                                             gatep, gatep, gatep, gatep, RR, DD, HD);
    chunk_prep<<<32 * NC, 64, 0, stream>>>(qb, kb, lfb, csb,
                                           ck_hat, ck_q, ck_kbT, ck_M, ck_G, ck_lam);
    chunk_scan<<<128, 64, 0, stream>>>(ck_hat, ck_q, ck_kbT, ck_M, ck_G, ck_lam, vb, obh);
    gate_ln_kernel<<<RR, blk, 0, stream>>>(obh, gatep, nw, lnob);
    gemm_bt<<<dim3(8, 32), blk, 0, stream>>>(lnob, WoT, WoT, WoT, WoT,
                                             out, out, out, out, RR, DD, DD);
}